// Round 1
// 597.499 us; speedup vs baseline: 1.3140x; 1.3140x over previous
//
#include <hip/hip_runtime.h>
#include <cstdint>
#include <cstddef>

typedef unsigned short u16;
typedef unsigned int u32;
typedef __attribute__((ext_vector_type(8))) short short8;   // 8 x bf16 (4 VGPRs)
typedef __attribute__((ext_vector_type(4))) float f32x4;    // MFMA accumulator

static constexpr int CB = 4;
static constexpr int CT = 8192;
static constexpr int CD = 512;
static constexpr int CH = 8;
static constexpr int CDH = 64;
static constexpr int CTE = 2048;
static constexpr int CD2 = 1024;

__device__ __forceinline__ float b2f(u16 u) {
    return __uint_as_float(((u32)u) << 16);
}
__device__ __forceinline__ u16 f2b(float f) {
    u32 i = __float_as_uint(f);
    i = i + 0x7fffu + ((i >> 16) & 1u);   // round-to-nearest-even
    return (u16)(i >> 16);
}

// ---------------------------------------------------------------- zero
__global__ __launch_bounds__(256) void zero_kernel(float* __restrict__ p, int n) {
    int i = blockIdx.x * 256 + threadIdx.x;
    if (i < n) p[i] = 0.0f;
}

// ---------------------------------------------------------------- W[k][n] fp32 -> Wt[n][k] bf16, tiled transpose
// grid = dim3(64, 4): 8x8 tiles of 64x64 per matrix; block 256
__global__ __launch_bounds__(256) void wconv_kernel(
        const float* __restrict__ W0, const float* __restrict__ W1,
        const float* __restrict__ W2, const float* __restrict__ W3,
        u16* __restrict__ Wt)
{
    const float* W;
    switch (blockIdx.y) {
        case 0: W = W0; break;
        case 1: W = W1; break;
        case 2: W = W2; break;
        default: W = W3; break;
    }
    u16* o = Wt + (size_t)blockIdx.y * CD * CD;
    const int k0 = (blockIdx.x >> 3) * 64;
    const int n0 = (blockIdx.x & 7) * 64;
    const int tid = threadIdx.x;
    __shared__ u16 tile[64][65];
    const int nn = tid & 63, kq = tid >> 6;
#pragma unroll
    for (int i = 0; i < 16; i++) {
        const int kk = i * 4 + kq;
        tile[kk][nn] = f2b(W[(size_t)(k0 + kk) * CD + n0 + nn]);  // coalesced read
    }
    __syncthreads();
    const int kk2 = tid & 63, nq = tid >> 6;
#pragma unroll
    for (int i = 0; i < 16; i++) {
        const int nn2 = i * 4 + nq;
        o[(size_t)(n0 + nn2) * CD + k0 + kk2] = tile[kk2][nn2];   // coalesced write
    }
}

// ---------------------------------------------------------------- LN1: fp32 x -> bf16 xn
__global__ __launch_bounds__(256) void ln1_kernel(const float* __restrict__ x,
        const float* __restrict__ g, const float* __restrict__ bt,
        u16* __restrict__ xn)
{
    const int row = blockIdx.x;
    const int tid = threadIdx.x;
    const float2 p = ((const float2*)(x + (size_t)row * CD))[tid];
    float s = p.x + p.y;
    float sq = p.x * p.x + p.y * p.y;
#pragma unroll
    for (int m = 1; m < 64; m <<= 1) { s += __shfl_xor(s, m); sq += __shfl_xor(sq, m); }
    __shared__ float red[8];
    const int wid = tid >> 6;
    if ((tid & 63) == 0) { red[wid] = s; red[wid + 4] = sq; }
    __syncthreads();
    s = red[0] + red[1] + red[2] + red[3];
    sq = red[4] + red[5] + red[6] + red[7];
    const float mu = s * (1.0f / CD);
    float var = sq * (1.0f / CD) - mu * mu;
    var = fmaxf(var, 0.0f);
    const float rs = rsqrtf(var + 1e-5f);
    const float2 gv = ((const float2*)g)[tid];
    const float2 bv = ((const float2*)bt)[tid];
    const float y0 = (p.x - mu) * rs * gv.x + bv.x;
    const float y1 = (p.y - mu) * rs * gv.y + bv.y;
    ((u32*)(xn + (size_t)row * CD))[tid] = (u32)f2b(y0) | ((u32)f2b(y1) << 16);
}

// ---------------------------------------------------------------- MFMA GEMM
// C[M,N] = A[M,K]bf16 @ Bt[N,K]bf16^T + bias, M=32768, N=K=512.
// mode 0 (q): out bf16 | mode 1 (k): +(1-mask)*-1e6, bf16 | mode 2 (v): *mask, bf16
// mode 3 (o): + xres, out fp32
// Tile 128x128, BK=32; 4 waves x (4x4 of 16x16x32). XOR-swizzled LDS.
__global__ __launch_bounds__(256) void gemm_mfma(
    const u16* __restrict__ A, const u16* __restrict__ Bt,
    const float* __restrict__ bias, void* __restrict__ Cv,
    const float* __restrict__ mask, const float* __restrict__ xres,
    int mode)
{
    __shared__ u16 As[4][128][8];   // 8 KB
    __shared__ u16 Bs[4][128][8];   // 8 KB
    const int tid = threadIdx.x;
    const int wave = tid >> 6, lane = tid & 63;
    const int quad = lane >> 4, l16 = lane & 15;
    const int row0 = blockIdx.y * 128;
    const int col0 = blockIdx.x * 128;
    const int wm = (wave >> 1) * 64, wn = (wave & 1) * 64;

    f32x4 acc[4][4];
#pragma unroll
    for (int mt = 0; mt < 4; mt++)
#pragma unroll
        for (int nt = 0; nt < 4; nt++)
            acc[mt][nt] = (f32x4){0.0f, 0.0f, 0.0f, 0.0f};

    const int koct = tid & 3;        // which 8-k octet this thread stages
    const int sm = tid >> 2;         // 0..63 dim index this thread stages

    for (int k0 = 0; k0 < CD; k0 += 32) {
        const u16* Ab = A + (size_t)(row0 + sm) * CD + k0 + koct * 8;
        const u16* Bb = Bt + (size_t)(col0 + sm) * CD + k0 + koct * 8;
        const uint4 a0 = *(const uint4*)Ab;
        const uint4 a1 = *(const uint4*)(Ab + (size_t)64 * CD);
        const uint4 b0 = *(const uint4*)Bb;
        const uint4 b1 = *(const uint4*)(Bb + (size_t)64 * CD);
        __syncthreads();
        *(uint4*)&As[koct][sm ^ koct][0] = a0;
        *(uint4*)&As[koct][(sm ^ koct) + 64][0] = a1;
        *(uint4*)&Bs[koct][sm ^ koct][0] = b0;
        *(uint4*)&Bs[koct][(sm ^ koct) + 64][0] = b1;
        __syncthreads();
        short8 af[4], bf[4];
#pragma unroll
        for (int mt = 0; mt < 4; mt++)
            af[mt] = *(const short8*)&As[quad][(wm + mt * 16) + (l16 ^ quad)][0];
#pragma unroll
        for (int nt = 0; nt < 4; nt++)
            bf[nt] = *(const short8*)&Bs[quad][(wn + nt * 16) + (l16 ^ quad)][0];
#pragma unroll
        for (int mt = 0; mt < 4; mt++)
#pragma unroll
            for (int nt = 0; nt < 4; nt++)
                acc[mt][nt] = __builtin_amdgcn_mfma_f32_16x16x32_bf16(
                    af[mt], bf[nt], acc[mt][nt], 0, 0, 0);
    }

    // epilogue: lane holds D[row=quad*4+r][col=l16] per tile
#pragma unroll
    for (int mt = 0; mt < 4; mt++) {
        const int rbase = row0 + wm + mt * 16 + quad * 4;
#pragma unroll
        for (int r = 0; r < 4; r++) {
            const int row = rbase + r;
            float mval = 0.0f;
            if (mode == 1 || mode == 2) mval = mask[row];
#pragma unroll
            for (int nt = 0; nt < 4; nt++) {
                const int col = col0 + wn + nt * 16 + l16;
                float val = acc[mt][nt][r] + bias[col];
                if (mode == 1) val += (1.0f - mval) * -1000000.0f;
                else if (mode == 2) val *= mval;
                if (mode == 3) {
                    ((float*)Cv)[(size_t)row * CD + col] =
                        val + xres[(size_t)row * CD + col];
                } else {
                    ((u16*)Cv)[(size_t)row * CD + col] = f2b(val);
                }
            }
        }
    }
}

// ---------------------------------------------------------------- k softmax over T: pass 1 partials
// grid = B(4) * chunks(8) * colgroups(8) = 256; block 256
__global__ __launch_bounds__(256) void ksm_partial(const u16* __restrict__ k,
        float* __restrict__ pm, float* __restrict__ ps)
{
    const int bid = blockIdx.x;
    const int b = bid >> 6, ch = (bid >> 3) & 7, cg = bid & 7;
    const int lane = threadIdx.x & 63, r = threadIdx.x >> 6;
    const int c = cg * 64 + lane;
    float m = -3.0e38f, s = 0.0f;
    const u16* base = k + (size_t)b * CT * CD + c;
    for (int t = ch * 1024 + r; t < (ch + 1) * 1024; t += 4) {
        const float xv = b2f(base[(size_t)t * CD]);
        const float nm = fmaxf(m, xv);
        s = s * __expf(m - nm) + __expf(xv - nm);
        m = nm;
    }
    __shared__ float Lm[4][64], Ls[4][64];
    Lm[r][lane] = m; Ls[r][lane] = s;
    __syncthreads();
    if (r == 0) {
        float M = Lm[0][lane];
#pragma unroll
        for (int qq = 1; qq < 4; qq++) M = fmaxf(M, Lm[qq][lane]);
        float S = 0.0f;
#pragma unroll
        for (int qq = 0; qq < 4; qq++) S += Ls[qq][lane] * __expf(Lm[qq][lane] - M);
        pm[((size_t)b * CD + c) * 8 + ch] = M;
        ps[((size_t)b * CD + c) * 8 + ch] = S;
    }
}

// pass 2: combine partials + normalize in place
// grid = B(4) * colgroups(8) * tchunks(16) = 512; block 256
__global__ __launch_bounds__(256) void ksm_norm(u16* __restrict__ k,
        const float* __restrict__ pm, const float* __restrict__ ps)
{
    const int bid = blockIdx.x;
    const int b = bid >> 7, cg = (bid >> 4) & 7, tch = bid & 15;
    const int tid = threadIdx.x;
    __shared__ float Ms[64], Rs[64];
    if (tid < 64) {
        const int d = cg * 64 + tid;
        const float* pmb = pm + ((size_t)b * CD + d) * 8;
        const float* psb = ps + ((size_t)b * CD + d) * 8;
        float M = pmb[0];
#pragma unroll
        for (int qq = 1; qq < 8; qq++) M = fmaxf(M, pmb[qq]);
        float S = 0.0f;
#pragma unroll
        for (int qq = 0; qq < 8; qq++) S += psb[qq] * __expf(pmb[qq] - M);
        Ms[tid] = M; Rs[tid] = 1.0f / S;
    }
    __syncthreads();
    const int lane = tid & 63, r = tid >> 6;
    const int c = cg * 64 + lane;
    const float M = Ms[lane], R = Rs[lane];
    u16* base = k + (size_t)b * CT * CD + c;
    for (int t = tch * 512 + r; t < (tch + 1) * 512; t += 4) {
        const size_t idx = (size_t)t * CD;
        base[idx] = f2b(__expf(b2f(base[idx]) - M) * R);
    }
}

// ---------------------------------------------------------------- attn = sum_t k (outer) v, per (b,h)
// grid = 32 (b,h) * 16 tchunks = 512; block 256
__global__ __launch_bounds__(256) void attn_kernel(const u16* __restrict__ k,
        const u16* __restrict__ v, float* __restrict__ attn)
{
    const int bid = blockIdx.x;
    const int bh = bid >> 4, ch = bid & 15;
    const int b = bh >> 3, h = bh & 7;
    const int tid = threadIdx.x;
    __shared__ u16 Ks[32][64], Vs[32][64];
    const int ti = tid >> 4, tj = tid & 15;
    const int d0 = ti * 4, l0 = tj * 4;
    const int trow = tid >> 3, cg8 = (tid & 7) * 8;
    float acc[4][4];
#pragma unroll
    for (int r = 0; r < 4; r++)
#pragma unroll
        for (int c = 0; c < 4; c++) acc[r][c] = 0.0f;

    for (int st = 0; st < 16; st++) {
        const int t0 = ch * 512 + st * 32;
        const size_t goff = ((size_t)(b * CT + t0 + trow)) * CD + h * 64 + cg8;
        const uint4 kv4 = *(const uint4*)(k + goff);
        const uint4 vv4 = *(const uint4*)(v + goff);
        __syncthreads();
        *(uint4*)&Ks[trow][cg8] = kv4;
        *(uint4*)&Vs[trow][cg8] = vv4;
        __syncthreads();
#pragma unroll
        for (int tt = 0; tt < 32; tt++) {
            const ushort4 ka = *(const ushort4*)&Ks[tt][d0];
            const ushort4 va = *(const ushort4*)&Vs[tt][l0];
            const float kr[4] = { b2f(ka.x), b2f(ka.y), b2f(ka.z), b2f(ka.w) };
            const float vr[4] = { b2f(va.x), b2f(va.y), b2f(va.z), b2f(va.w) };
#pragma unroll
            for (int r = 0; r < 4; r++)
#pragma unroll
                for (int c = 0; c < 4; c++)
                    acc[r][c] = fmaf(kr[r], vr[c], acc[r][c]);
        }
    }
    float* ab = attn + (size_t)bh * 64 * 64;
#pragma unroll
    for (int r = 0; r < 4; r++)
#pragma unroll
        for (int c = 0; c < 4; c++)
            atomicAdd(&ab[(d0 + r) * 64 + l0 + c], acc[r][c]);
}

// ---------------------------------------------------------------- y = softmax(q over Dh) @ attn  (MFMA)
// grid = 32 (b,h) * 32 rowchunks = 1024; block 256 (4 waves), each wave 64 rows.
// attn[b,h] (64x64 fp32) split hi/lo bf16, transposed to Bt[col][k] in LDS, held
// in registers as B-frags for the whole block. qs split hi/lo too; 3 MFMA terms
// (qh*ah + qh*al + ql*ah) give ~fp32 accuracy.
__global__ __launch_bounds__(256) void y_mfma(const u16* __restrict__ q,
        const float* __restrict__ attn, u16* __restrict__ y)
{
    const int bid = blockIdx.x;
    const int bh = bid >> 5;          // 0..31
    const int chunk = bid & 31;       // 0..31
    const int b = bh >> 3, h = bh & 7;
    const int tid = threadIdx.x;
    const int wave = tid >> 6, lane = tid & 63;
    const int quad = lane >> 4, l16 = lane & 15;

    __shared__ u16 Bh[64][72];        // Bt layout: [col l][k d], +8 pad (16B) keeps b128 align
    __shared__ u16 Bl[64][72];
    __shared__ float Ys[4][16][65];   // per-wave epilogue staging, padded

    const float* ab = attn + (size_t)bh * 64 * 64;
#pragma unroll
    for (int i = 0; i < 16; i++) {
        const int idx = i * 256 + tid;
        const int d = idx >> 6, l = idx & 63;
        const float a = ab[idx];
        const u16 hi = f2b(a);
        Bh[l][d] = hi;
        Bl[l][d] = f2b(a - b2f(hi));
    }
    __syncthreads();

    // B-frags: lane (quad,l16) holds Bt[col = nt*16+l16][k = ks*32 + quad*8 .. +8]
    short8 bhf[4][2], blf[4][2];
#pragma unroll
    for (int nt = 0; nt < 4; nt++)
#pragma unroll
        for (int ks = 0; ks < 2; ks++) {
            bhf[nt][ks] = *(const short8*)&Bh[nt * 16 + l16][ks * 32 + quad * 8];
            blf[nt][ks] = *(const short8*)&Bl[nt * 16 + l16][ks * 32 + quad * 8];
        }

    const int rowbase = chunk * 256 + wave * 64;            // within this batch
    const size_t qb = ((size_t)(b * CT + rowbase)) * CD + h * 64;

#pragma unroll
    for (int it = 0; it < 4; it++) {
        // A: lane (quad,l16) loads q[row = it*16+l16][k = quad*8..] and [32+quad*8..]
        const u16* qp = q + qb + (size_t)(it * 16 + l16) * CD + quad * 8;
        const uint4 q0 = *(const uint4*)qp;
        const uint4 q1 = *(const uint4*)(qp + 32);
        float xv[16];
        const u32 qw[8] = { q0.x, q0.y, q0.z, q0.w, q1.x, q1.y, q1.z, q1.w };
#pragma unroll
        for (int j = 0; j < 8; j++) {
            xv[2 * j]     = b2f((u16)(qw[j] & 0xffff));
            xv[2 * j + 1] = b2f((u16)(qw[j] >> 16));
        }
        // row softmax: 16 in-lane values + reduce across the 4 quads of this row
        float m = xv[0];
#pragma unroll
        for (int j = 1; j < 16; j++) m = fmaxf(m, xv[j]);
        m = fmaxf(m, __shfl_xor(m, 16));
        m = fmaxf(m, __shfl_xor(m, 32));
        float s = 0.0f;
#pragma unroll
        for (int j = 0; j < 16; j++) { xv[j] = __expf(xv[j] - m); s += xv[j]; }
        s += __shfl_xor(s, 16);
        s += __shfl_xor(s, 32);
        const float rinv = 1.0f / s;
        short8 ah[2], al[2];
#pragma unroll
        for (int ks = 0; ks < 2; ks++)
#pragma unroll
            for (int j = 0; j < 8; j++) {
                const float v = xv[ks * 8 + j] * rinv;
                const u16 hi = f2b(v);
                ah[ks][j] = (short)hi;
                al[ks][j] = (short)f2b(v - b2f(hi));
            }

        f32x4 acc[4];
#pragma unroll
        for (int nt = 0; nt < 4; nt++) acc[nt] = (f32x4){0.f, 0.f, 0.f, 0.f};
#pragma unroll
        for (int nt = 0; nt < 4; nt++) {
            acc[nt] = __builtin_amdgcn_mfma_f32_16x16x32_bf16(ah[0], bhf[nt][0], acc[nt], 0, 0, 0);
            acc[nt] = __builtin_amdgcn_mfma_f32_16x16x32_bf16(ah[1], bhf[nt][1], acc[nt], 0, 0, 0);
            acc[nt] = __builtin_amdgcn_mfma_f32_16x16x32_bf16(ah[0], blf[nt][0], acc[nt], 0, 0, 0);
            acc[nt] = __builtin_amdgcn_mfma_f32_16x16x32_bf16(ah[1], blf[nt][1], acc[nt], 0, 0, 0);
            acc[nt] = __builtin_amdgcn_mfma_f32_16x16x32_bf16(al[0], bhf[nt][0], acc[nt], 0, 0, 0);
            acc[nt] = __builtin_amdgcn_mfma_f32_16x16x32_bf16(al[1], bhf[nt][1], acc[nt], 0, 0, 0);
        }

        // stage to LDS (per-wave region, no barrier needed), then coalesced packed stores
#pragma unroll
        for (int nt = 0; nt < 4; nt++)
#pragma unroll
            for (int rr = 0; rr < 4; rr++)
                Ys[wave][quad * 4 + rr][nt * 16 + l16] = acc[nt][rr];
        // 16 rows x 64 bf16 = 512 u32; 8 passes of 64 lanes
        u32* yo = (u32*)y + ((size_t)(b * CT + rowbase + it * 16)) * (CD / 2) + h * 32;
#pragma unroll
        for (int p = 0; p < 8; p++) {
            const int idx = p * 64 + lane;
            const int row = idx >> 5, c2 = idx & 31;
            const float f0 = Ys[wave][row][2 * c2];
            const float f1 = Ys[wave][row][2 * c2 + 1];
            yo[(size_t)row * (CD / 2) + c2] = (u32)f2b(f0) | ((u32)f2b(f1) << 16);
        }
    }
}

// ---------------------------------------------------------------- emb pipeline
// se = silu(emb): 8192 elements
__global__ __launch_bounds__(256) void embsilu_kernel(const float* __restrict__ emb,
        float* __restrict__ se)
{
    const int i = blockIdx.x * 256 + threadIdx.x;
    if (i < CB * CTE) {
        const float e = emb[i];
        se[i] = e / (1.0f + __expf(-e));
    }
}
// eo = embB broadcast per batch: 4096 elements
__global__ __launch_bounds__(256) void eoinit_kernel(const float* __restrict__ embB,
        float* __restrict__ eo)
{
    const int i = blockIdx.x * 256 + threadIdx.x;
    if (i < CB * CD2) eo[i] = embB[i & (CD2 - 1)];
}
// eo += se @ embW for all 4 batches.
// grid = 128 (16 jgroups x 8 kchunks); block 256 = 64 j x 4 ksubs.
// embW read exactly once, coalesced 256 B per wave-step.
__global__ __launch_bounds__(256) void embout2_kernel(const float* __restrict__ se,
        const float* __restrict__ embW, float* __restrict__ eo)
{
    const int jg = blockIdx.x & 15, kc = blockIdx.x >> 4;
    const int tid = threadIdx.x;
    const int jl = tid & 63, kgrp = tid >> 6;
    const int j = jg * 64 + jl;
    const int kbase = kc * 256 + kgrp * 64;
    const float* W = embW + (size_t)kbase * CD2 + j;
    const float* s0 = se + kbase;
    const float* s1 = s0 + CTE;
    const float* s2 = s1 + CTE;
    const float* s3 = s2 + CTE;
    float a0 = 0.0f, a1 = 0.0f, a2 = 0.0f, a3 = 0.0f;
#pragma unroll 8
    for (int kk = 0; kk < 64; kk++) {
        const float w = W[(size_t)kk * CD2];
        a0 = fmaf(s0[kk], w, a0);
        a1 = fmaf(s1[kk], w, a1);
        a2 = fmaf(s2[kk], w, a2);
        a3 = fmaf(s3[kk], w, a3);
    }
    __shared__ float red[4][4][64];   // [kgrp][b][j]
    red[kgrp][0][jl] = a0; red[kgrp][1][jl] = a1;
    red[kgrp][2][jl] = a2; red[kgrp][3][jl] = a3;
    __syncthreads();
    if (tid < 64) {
#pragma unroll
        for (int b = 0; b < 4; b++) {
            const float t = red[0][b][tid] + red[1][b][tid]
                          + red[2][b][tid] + red[3][b][tid];
            atomicAdd(&eo[(size_t)b * CD2 + jg * 64 + tid], t);
        }
    }
}

// ---------------------------------------------------------------- LN2 + stylization + silu: y bf16 -> s bf16
__global__ __launch_bounds__(256) void ln2_style_kernel(const u16* __restrict__ y,
        const float* __restrict__ g2, const float* __restrict__ bt2,
        const float* __restrict__ eo, u16* __restrict__ sout)
{
    const int row = blockIdx.x;
    const int tid = threadIdx.x;
    const int b = row >> 13;
    const u32 p = ((const u32*)(y + (size_t)row * CD))[tid];
    const float x0 = b2f((u16)(p & 0xffff));
    const float x1 = b2f((u16)(p >> 16));
    float s = x0 + x1;
    float sq = x0 * x0 + x1 * x1;
#pragma unroll
    for (int m = 1; m < 64; m <<= 1) { s += __shfl_xor(s, m); sq += __shfl_xor(sq, m); }
    __shared__ float red[8];
    const int wid = tid >> 6;
    if ((tid & 63) == 0) { red[wid] = s; red[wid + 4] = sq; }
    __syncthreads();
    s = red[0] + red[1] + red[2] + red[3];
    sq = red[4] + red[5] + red[6] + red[7];
    const float mu = s * (1.0f / CD);
    float var = sq * (1.0f / CD) - mu * mu;
    var = fmaxf(var, 0.0f);
    const float rs = rsqrtf(var + 1e-5f);
    const float2 gv = ((const float2*)g2)[tid];
    const float2 bv = ((const float2*)bt2)[tid];
    const float2 sc = ((const float2*)(eo + (size_t)b * CD2))[tid];
    const float2 sh = ((const float2*)(eo + (size_t)b * CD2 + CD))[tid];
    float h0 = (x0 - mu) * rs * gv.x + bv.x;
    float h1 = (x1 - mu) * rs * gv.y + bv.y;
    h0 = h0 * (1.0f + sc.x) + sh.x;
    h1 = h1 * (1.0f + sc.y) + sh.y;
    const float s0 = h0 / (1.0f + __expf(-h0));
    const float s1 = h1 / (1.0f + __expf(-h1));
    ((u32*)(sout + (size_t)row * CD))[tid] = (u32)f2b(s0) | ((u32)f2b(s1) << 16);
}

// ----------------------------------------------------------------
// Buffers:
//  d_out (64 MB fp32 out) as scratch until final GEMM:
//    R0 [0,32M):  k bf16 -> q bf16 (k dead after attn_kernel)
//    R1 [32M,64M): v bf16 -> y bf16 (v dead after attn_kernel)
//  d_ws (~36.4 MB used):
//    ws+0        : xn bf16 (32 MB) -> s bf16 (xn dead after q-GEMM)
//    ws+33554432 : Wt bf16 x4 [n][k]: Wk,Wv,Wq,outW (2 MB)
//    ws+35651584 : attn (512 KB fp32)
//    ws+36175872 : pm (64 KB)
//    ws+36241408 : ps (64 KB)
//    ws+36306944 : eo (16 KB fp32)
//    ws+36323328 : se (32 KB fp32, silu(emb))
extern "C" void kernel_launch(void* const* d_in, const int* in_sizes, int n_in,
                              void* d_out, int out_size, void* d_ws, size_t ws_size,
                              hipStream_t stream) {
    (void)in_sizes; (void)n_in; (void)out_size; (void)ws_size;
    const float* x    = (const float*)d_in[0];
    const float* emb  = (const float*)d_in[1];
    const float* mask = (const float*)d_in[2];
    const float* gamma= (const float*)d_in[3];
    const float* beta = (const float*)d_in[4];
    const float* Wq   = (const float*)d_in[5];
    const float* bq   = (const float*)d_in[6];
    const float* Wk   = (const float*)d_in[7];
    const float* bk   = (const float*)d_in[8];
    const float* Wv   = (const float*)d_in[9];
    const float* bv   = (const float*)d_in[10];
    const float* embW = (const float*)d_in[11];
    const float* embB = (const float*)d_in[12];
    const float* g2   = (const float*)d_in[13];
    const float* bt2  = (const float*)d_in[14];
    const float* outW = (const float*)d_in[15];
    const float* outb = (const float*)d_in[16];

    char* od = (char*)d_out;
    u16* kq  = (u16*)od;                        // R0: k then q
    u16* vy  = (u16*)(od + 33554432);           // R1: v then y
    float* outp = (float*)d_out;

    char* ws = (char*)d_ws;
    u16* xn   = (u16*)ws;                       // 32 MB, later s
    u16* WtK  = (u16*)(ws + 33554432);
    u16* WtV  = WtK + (size_t)CD * CD;
    u16* WtQ  = WtV + (size_t)CD * CD;
    u16* WtO  = WtQ + (size_t)CD * CD;
    float* attn = (float*)(ws + 35651584);
    float* pm   = (float*)(ws + 36175872);
    float* ps   = (float*)(ws + 36241408);
    float* eo   = (float*)(ws + 36306944);
    float* se   = (float*)(ws + 36323328);

    dim3 gg(CD / 128, (CB * CT) / 128);         // (4, 256)

    wconv_kernel<<<dim3(64, 4), 256, 0, stream>>>(Wk, Wv, Wq, outW, WtK);
    ln1_kernel<<<CB * CT, 256, 0, stream>>>(x, gamma, beta, xn);
    zero_kernel<<<512, 256, 0, stream>>>(attn, CB * CH * CDH * CDH);
    embsilu_kernel<<<32, 256, 0, stream>>>(emb, se);
    eoinit_kernel<<<16, 256, 0, stream>>>(embB, eo);
    embout2_kernel<<<128, 256, 0, stream>>>(se, embW, eo);
    gemm_mfma<<<gg, 256, 0, stream>>>(xn, WtK, bk, kq, mask, nullptr, 1);
    ksm_partial<<<256, 256, 0, stream>>>(kq, pm, ps);
    ksm_norm<<<512, 256, 0, stream>>>(kq, pm, ps);
    gemm_mfma<<<gg, 256, 0, stream>>>(xn, WtV, bv, vy, mask, nullptr, 2);
    attn_kernel<<<512, 256, 0, stream>>>(kq, vy, attn);
    // k, v dead -> q into R0, y into R1
    gemm_mfma<<<gg, 256, 0, stream>>>(xn, WtQ, bq, kq, nullptr, nullptr, 0);
    y_mfma<<<1024, 256, 0, stream>>>(kq, attn, vy);
    ln2_style_kernel<<<CB * CT, 256, 0, stream>>>(vy, g2, bt2, eo, xn /* s */);
    gemm_mfma<<<gg, 256, 0, stream>>>(xn /* s */, WtO, outb, outp, nullptr, x, 3);
}

// Round 2
// 528.070 us; speedup vs baseline: 1.4868x; 1.1315x over previous
//
#include <hip/hip_runtime.h>
#include <cstdint>
#include <cstddef>

typedef unsigned short u16;
typedef unsigned int u32;
typedef __attribute__((ext_vector_type(8))) short short8;   // 8 x bf16 (4 VGPRs)
typedef __attribute__((ext_vector_type(4))) float f32x4;    // MFMA accumulator

static constexpr int CB = 4;
static constexpr int CT = 8192;
static constexpr int CD = 512;
static constexpr int CH = 8;
static constexpr int CDH = 64;
static constexpr int CTE = 2048;
static constexpr int CD2 = 1024;

__device__ __forceinline__ float b2f(u16 u) {
    return __uint_as_float(((u32)u) << 16);
}
__device__ __forceinline__ u16 f2b(float f) {
    u32 i = __float_as_uint(f);
    i = i + 0x7fffu + ((i >> 16) & 1u);   // round-to-nearest-even
    return (u16)(i >> 16);
}

typedef const __attribute__((address_space(1))) void* gas_p;
typedef __attribute__((address_space(3))) void* las_p;
#define GLD16(g, l) __builtin_amdgcn_global_load_lds((gas_p)(g), (las_p)(l), 16, 0, 0)

// ---------------------------------------------------------------- zero
__global__ __launch_bounds__(256) void zero_kernel(float* __restrict__ p, int n) {
    int i = blockIdx.x * 256 + threadIdx.x;
    if (i < n) p[i] = 0.0f;
}

// ---------------------------------------------------------------- W[k][n] fp32 -> Wt[n][k] bf16, tiled transpose
// grid = dim3(64, 4): 8x8 tiles of 64x64 per matrix; block 256
__global__ __launch_bounds__(256) void wconv_kernel(
        const float* __restrict__ W0, const float* __restrict__ W1,
        const float* __restrict__ W2, const float* __restrict__ W3,
        u16* __restrict__ Wt)
{
    const float* W;
    switch (blockIdx.y) {
        case 0: W = W0; break;
        case 1: W = W1; break;
        case 2: W = W2; break;
        default: W = W3; break;
    }
    u16* o = Wt + (size_t)blockIdx.y * CD * CD;
    const int k0 = (blockIdx.x >> 3) * 64;
    const int n0 = (blockIdx.x & 7) * 64;
    const int tid = threadIdx.x;
    __shared__ u16 tile[64][65];
    const int nn = tid & 63, kq = tid >> 6;
#pragma unroll
    for (int i = 0; i < 16; i++) {
        const int kk = i * 4 + kq;
        tile[kk][nn] = f2b(W[(size_t)(k0 + kk) * CD + n0 + nn]);  // coalesced read
    }
    __syncthreads();
    const int kk2 = tid & 63, nq = tid >> 6;
#pragma unroll
    for (int i = 0; i < 16; i++) {
        const int nn2 = i * 4 + nq;
        o[(size_t)(n0 + nn2) * CD + k0 + kk2] = tile[kk2][nn2];   // coalesced write
    }
}

// ---------------------------------------------------------------- LN1: fp32 x -> bf16 xn
__global__ __launch_bounds__(256) void ln1_kernel(const float* __restrict__ x,
        const float* __restrict__ g, const float* __restrict__ bt,
        u16* __restrict__ xn)
{
    const int row = blockIdx.x;
    const int tid = threadIdx.x;
    const float2 p = ((const float2*)(x + (size_t)row * CD))[tid];
    float s = p.x + p.y;
    float sq = p.x * p.x + p.y * p.y;
#pragma unroll
    for (int m = 1; m < 64; m <<= 1) { s += __shfl_xor(s, m); sq += __shfl_xor(sq, m); }
    __shared__ float red[8];
    const int wid = tid >> 6;
    if ((tid & 63) == 0) { red[wid] = s; red[wid + 4] = sq; }
    __syncthreads();
    s = red[0] + red[1] + red[2] + red[3];
    sq = red[4] + red[5] + red[6] + red[7];
    const float mu = s * (1.0f / CD);
    float var = sq * (1.0f / CD) - mu * mu;
    var = fmaxf(var, 0.0f);
    const float rs = rsqrtf(var + 1e-5f);
    const float2 gv = ((const float2*)g)[tid];
    const float2 bv = ((const float2*)bt)[tid];
    const float y0 = (p.x - mu) * rs * gv.x + bv.x;
    const float y1 = (p.y - mu) * rs * gv.y + bv.y;
    ((u32*)(xn + (size_t)row * CD))[tid] = (u32)f2b(y0) | ((u32)f2b(y1) << 16);
}

// ---------------------------------------------------------------- MFMA GEMM
// C[M,N] = A[M,K]bf16 @ Bt[N,K]bf16^T + bias, M=32768, N=K=512.
// mode 0 (q): out bf16 | mode 1 (k): +(1-mask)*-1e6, bf16 | mode 2 (v): *mask, bf16
// mode 3 (o): + xres, out fp32
// Tile 128x128, BK=32. 2-phase double-buffered global_load_lds pipeline (T3 min),
// XCD-aware 1D block swizzle (T1). LDS row-major [row][32k]: full-wave b128
// fragment reads cover contiguous 1KB -> conflict-free, linear dest for DMA.
__global__ __launch_bounds__(256) void gemm_mfma(
    const u16* __restrict__ A, const u16* __restrict__ Bt,
    const float* __restrict__ bias, void* __restrict__ Cv,
    const float* __restrict__ mask, const float* __restrict__ xres,
    int mode)
{
    __shared__ u16 As[2][128][32];   // 8 KB per buffer
    __shared__ u16 Bs[2][128][32];
    const int tid = threadIdx.x;
    const int wave = tid >> 6, lane = tid & 63;
    const int quad = lane >> 4, l16 = lane & 15;

    // XCD swizzle: grid = 1024 (1D). xcd = n&7; each XCD gets 32 consecutive
    // row-panels x 4 col-blocks -> A panel fetched once per XCD L2.
    const int n = blockIdx.x;
    const int xcd = n & 7, slot = n >> 3;        // slot 0..127
    const int by = xcd * 32 + (slot >> 2);       // 0..255
    const int bx = slot & 3;                     // 0..3
    const int row0 = by * 128;
    const int col0 = bx * 128;
    const int wm = (wave >> 1) * 64, wn = (wave & 1) * 64;

    f32x4 acc[4][4];
#pragma unroll
    for (int mt = 0; mt < 4; mt++)
#pragma unroll
        for (int nt = 0; nt < 4; nt++)
            acc[mt][nt] = (f32x4){0.0f, 0.0f, 0.0f, 0.0f};

    // staging: wave w stages rows [w*16, w*16+16) and [w*16+64, ...) of A and B.
    // lane l -> row sub = l>>2, 16B slot = l&3 (linear LDS dest = base + l*16).
    const int srow = lane >> 2;
    const int scol = lane & 3;
    const int aw0 = wave * 16;
    const u16* gA0 = A + (size_t)(row0 + aw0 + srow) * CD + scol * 8;
    const u16* gA1 = gA0 + (size_t)64 * CD;
    const u16* gB0 = Bt + (size_t)(col0 + aw0 + srow) * CD + scol * 8;
    const u16* gB1 = gB0 + (size_t)64 * CD;

#define STAGE_T(bf, ko) do { \
        GLD16(gA0 + (ko), &As[bf][aw0][0]); \
        GLD16(gA1 + (ko), &As[bf][aw0 + 64][0]); \
        GLD16(gB0 + (ko), &Bs[bf][aw0][0]); \
        GLD16(gB1 + (ko), &Bs[bf][aw0 + 64][0]); \
    } while (0)

    STAGE_T(0, 0);
    __syncthreads();

    for (int t = 0; t < 16; ++t) {
        const int cur = t & 1;
        if (t < 15) STAGE_T(cur ^ 1, (t + 1) * 32);   // prefetch next K-tile
        short8 af[4], bfr[4];
#pragma unroll
        for (int mt = 0; mt < 4; mt++)
            af[mt] = *(const short8*)&As[cur][wm + mt * 16 + l16][quad * 8];
#pragma unroll
        for (int nt = 0; nt < 4; nt++)
            bfr[nt] = *(const short8*)&Bs[cur][wn + nt * 16 + l16][quad * 8];
#pragma unroll
        for (int mt = 0; mt < 4; mt++)
#pragma unroll
            for (int nt = 0; nt < 4; nt++)
                acc[mt][nt] = __builtin_amdgcn_mfma_f32_16x16x32_bf16(
                    af[mt], bfr[nt], acc[mt][nt], 0, 0, 0);
        __syncthreads();   // vmcnt(0)+lgkmcnt(0)+barrier: prefetch landed, LDS reads done
    }
#undef STAGE_T

    // epilogue: lane holds D[row=quad*4+r][col=l16] per tile
#pragma unroll
    for (int mt = 0; mt < 4; mt++) {
        const int rbase = row0 + wm + mt * 16 + quad * 4;
#pragma unroll
        for (int r = 0; r < 4; r++) {
            const int row = rbase + r;
            float mval = 0.0f;
            if (mode == 1 || mode == 2) mval = mask[row];
#pragma unroll
            for (int nt = 0; nt < 4; nt++) {
                const int col = col0 + wn + nt * 16 + l16;
                float val = acc[mt][nt][r] + bias[col];
                if (mode == 1) val += (1.0f - mval) * -1000000.0f;
                else if (mode == 2) val *= mval;
                if (mode == 3) {
                    ((float*)Cv)[(size_t)row * CD + col] =
                        val + xres[(size_t)row * CD + col];
                } else {
                    ((u16*)Cv)[(size_t)row * CD + col] = f2b(val);
                }
            }
        }
    }
}

// ---------------------------------------------------------------- k softmax over T (row-coalesced)
// pass 1: per-chunk max/sum partials. grid = B(4)*chunks(32) = 128; block 256.
// Each thread owns one u32 col-pair; rows read coalesced (1 KB per wave-step).
__global__ __launch_bounds__(256) void ksm_partial(const u16* __restrict__ k,
        float* __restrict__ pm, float* __restrict__ ps)
{
    const int bid = blockIdx.x;
    const int b = bid >> 5, ch = bid & 31;
    const int tid = threadIdx.x;
    const u32* base = (const u32*)(k + (size_t)b * CT * CD + (size_t)ch * 256 * CD) + tid;
    float m0 = -3.0e38f, m1 = -3.0e38f;
#pragma unroll 8
    for (int r = 0; r < 256; ++r) {
        const u32 p = base[(size_t)r * 256];
        m0 = fmaxf(m0, b2f((u16)(p & 0xffff)));
        m1 = fmaxf(m1, b2f((u16)(p >> 16)));
    }
    float s0 = 0.0f, s1 = 0.0f;
#pragma unroll 8
    for (int r = 0; r < 256; ++r) {
        const u32 p = base[(size_t)r * 256];   // L2-resident re-read (256 KB/block)
        s0 += __expf(b2f((u16)(p & 0xffff)) - m0);
        s1 += __expf(b2f((u16)(p >> 16)) - m1);
    }
    const int d0 = tid * 2;
    pm[((size_t)b * CD + d0) * 32 + ch] = m0;
    pm[((size_t)b * CD + d0 + 1) * 32 + ch] = m1;
    ps[((size_t)b * CD + d0) * 32 + ch] = s0;
    ps[((size_t)b * CD + d0 + 1) * 32 + ch] = s1;
}

// pass 2: combine partials + normalize in place (row-coalesced).
// grid = B(4)*chunks(32) = 128; block 256.
__global__ __launch_bounds__(256) void ksm_norm(u16* __restrict__ k,
        const float* __restrict__ pm, const float* __restrict__ ps)
{
    const int bid = blockIdx.x;
    const int b = bid >> 5, ch = bid & 31;
    const int tid = threadIdx.x;
    const int d0 = tid * 2;
    const float* pm0 = pm + ((size_t)b * CD + d0) * 32;
    const float* pm1 = pm0 + 32;
    const float* ps0 = ps + ((size_t)b * CD + d0) * 32;
    const float* ps1 = ps0 + 32;
    float M0 = -3.0e38f, M1 = -3.0e38f;
#pragma unroll
    for (int c = 0; c < 32; ++c) { M0 = fmaxf(M0, pm0[c]); M1 = fmaxf(M1, pm1[c]); }
    float S0 = 0.0f, S1 = 0.0f;
#pragma unroll
    for (int c = 0; c < 32; ++c) {
        S0 += ps0[c] * __expf(pm0[c] - M0);
        S1 += ps1[c] * __expf(pm1[c] - M1);
    }
    const float R0 = 1.0f / S0, R1 = 1.0f / S1;
    u32* base = (u32*)(k + (size_t)b * CT * CD + (size_t)ch * 256 * CD) + tid;
#pragma unroll 4
    for (int r = 0; r < 256; ++r) {
        const u32 p = base[(size_t)r * 256];
        const float x0 = __expf(b2f((u16)(p & 0xffff)) - M0) * R0;
        const float x1 = __expf(b2f((u16)(p >> 16)) - M1) * R1;
        base[(size_t)r * 256] = (u32)f2b(x0) | ((u32)f2b(x1) << 16);
    }
}

// ---------------------------------------------------------------- attn = sum_t k (outer) v, per (b,h)
// grid = 32 (b,h) * 16 tchunks = 512; block 256
__global__ __launch_bounds__(256) void attn_kernel(const u16* __restrict__ k,
        const u16* __restrict__ v, float* __restrict__ attn)
{
    const int bid = blockIdx.x;
    const int bh = bid >> 4, ch = bid & 15;
    const int b = bh >> 3, h = bh & 7;
    const int tid = threadIdx.x;
    __shared__ u16 Ks[32][64], Vs[32][64];
    const int ti = tid >> 4, tj = tid & 15;
    const int d0 = ti * 4, l0 = tj * 4;
    const int trow = tid >> 3, cg8 = (tid & 7) * 8;
    float acc[4][4];
#pragma unroll
    for (int r = 0; r < 4; r++)
#pragma unroll
        for (int c = 0; c < 4; c++) acc[r][c] = 0.0f;

    for (int st = 0; st < 16; st++) {
        const int t0 = ch * 512 + st * 32;
        const size_t goff = ((size_t)(b * CT + t0 + trow)) * CD + h * 64 + cg8;
        const uint4 kv4 = *(const uint4*)(k + goff);
        const uint4 vv4 = *(const uint4*)(v + goff);
        __syncthreads();
        *(uint4*)&Ks[trow][cg8] = kv4;
        *(uint4*)&Vs[trow][cg8] = vv4;
        __syncthreads();
#pragma unroll
        for (int tt = 0; tt < 32; tt++) {
            const ushort4 ka = *(const ushort4*)&Ks[tt][d0];
            const ushort4 va = *(const ushort4*)&Vs[tt][l0];
            const float kr[4] = { b2f(ka.x), b2f(ka.y), b2f(ka.z), b2f(ka.w) };
            const float vr[4] = { b2f(va.x), b2f(va.y), b2f(va.z), b2f(va.w) };
#pragma unroll
            for (int r = 0; r < 4; r++)
#pragma unroll
                for (int c = 0; c < 4; c++)
                    acc[r][c] = fmaf(kr[r], vr[c], acc[r][c]);
        }
    }
    float* ab = attn + (size_t)bh * 64 * 64;
#pragma unroll
    for (int r = 0; r < 4; r++)
#pragma unroll
        for (int c = 0; c < 4; c++)
            atomicAdd(&ab[(d0 + r) * 64 + l0 + c], acc[r][c]);
}

// ---------------------------------------------------------------- y = softmax(q over Dh) @ attn  (MFMA)
// grid = 32 (b,h) * 32 rowchunks = 1024; block 256 (4 waves), each wave 64 rows.
__global__ __launch_bounds__(256) void y_mfma(const u16* __restrict__ q,
        const float* __restrict__ attn, u16* __restrict__ y)
{
    const int bid = blockIdx.x;
    const int bh = bid >> 5;          // 0..31
    const int chunk = bid & 31;       // 0..31
    const int b = bh >> 3, h = bh & 7;
    const int tid = threadIdx.x;
    const int wave = tid >> 6, lane = tid & 63;
    const int quad = lane >> 4, l16 = lane & 15;

    __shared__ u16 Bh[64][72];        // Bt layout: [col l][k d], +8 pad keeps b128 align
    __shared__ u16 Bl[64][72];
    __shared__ float Ys[4][16][65];   // per-wave epilogue staging, padded

    const float* ab = attn + (size_t)bh * 64 * 64;
#pragma unroll
    for (int i = 0; i < 16; i++) {
        const int idx = i * 256 + tid;
        const int d = idx >> 6, l = idx & 63;
        const float a = ab[idx];
        const u16 hi = f2b(a);
        Bh[l][d] = hi;
        Bl[l][d] = f2b(a - b2f(hi));
    }
    __syncthreads();

    short8 bhf[4][2], blf[4][2];
#pragma unroll
    for (int nt = 0; nt < 4; nt++)
#pragma unroll
        for (int ks = 0; ks < 2; ks++) {
            bhf[nt][ks] = *(const short8*)&Bh[nt * 16 + l16][ks * 32 + quad * 8];
            blf[nt][ks] = *(const short8*)&Bl[nt * 16 + l16][ks * 32 + quad * 8];
        }

    const int rowbase = chunk * 256 + wave * 64;            // within this batch
    const size_t qb = ((size_t)(b * CT + rowbase)) * CD + h * 64;

#pragma unroll
    for (int it = 0; it < 4; it++) {
        const u16* qp = q + qb + (size_t)(it * 16 + l16) * CD + quad * 8;
        const uint4 q0 = *(const uint4*)qp;
        const uint4 q1 = *(const uint4*)(qp + 32);
        float xv[16];
        const u32 qw[8] = { q0.x, q0.y, q0.z, q0.w, q1.x, q1.y, q1.z, q1.w };
#pragma unroll
        for (int j = 0; j < 8; j++) {
            xv[2 * j]     = b2f((u16)(qw[j] & 0xffff));
            xv[2 * j + 1] = b2f((u16)(qw[j] >> 16));
        }
        float m = xv[0];
#pragma unroll
        for (int j = 1; j < 16; j++) m = fmaxf(m, xv[j]);
        m = fmaxf(m, __shfl_xor(m, 16));
        m = fmaxf(m, __shfl_xor(m, 32));
        float s = 0.0f;
#pragma unroll
        for (int j = 0; j < 16; j++) { xv[j] = __expf(xv[j] - m); s += xv[j]; }
        s += __shfl_xor(s, 16);
        s += __shfl_xor(s, 32);
        const float rinv = 1.0f / s;
        short8 ah[2], al[2];
#pragma unroll
        for (int ks = 0; ks < 2; ks++)
#pragma unroll
            for (int j = 0; j < 8; j++) {
                const float v = xv[ks * 8 + j] * rinv;
                const u16 hi = f2b(v);
                ah[ks][j] = (short)hi;
                al[ks][j] = (short)f2b(v - b2f(hi));
            }

        f32x4 acc[4];
#pragma unroll
        for (int nt = 0; nt < 4; nt++) acc[nt] = (f32x4){0.f, 0.f, 0.f, 0.f};
#pragma unroll
        for (int nt = 0; nt < 4; nt++) {
            acc[nt] = __builtin_amdgcn_mfma_f32_16x16x32_bf16(ah[0], bhf[nt][0], acc[nt], 0, 0, 0);
            acc[nt] = __builtin_amdgcn_mfma_f32_16x16x32_bf16(ah[1], bhf[nt][1], acc[nt], 0, 0, 0);
            acc[nt] = __builtin_amdgcn_mfma_f32_16x16x32_bf16(ah[0], blf[nt][0], acc[nt], 0, 0, 0);
            acc[nt] = __builtin_amdgcn_mfma_f32_16x16x32_bf16(ah[1], blf[nt][1], acc[nt], 0, 0, 0);
            acc[nt] = __builtin_amdgcn_mfma_f32_16x16x32_bf16(al[0], bhf[nt][0], acc[nt], 0, 0, 0);
            acc[nt] = __builtin_amdgcn_mfma_f32_16x16x32_bf16(al[1], bhf[nt][1], acc[nt], 0, 0, 0);
        }

#pragma unroll
        for (int nt = 0; nt < 4; nt++)
#pragma unroll
            for (int rr = 0; rr < 4; rr++)
                Ys[wave][quad * 4 + rr][nt * 16 + l16] = acc[nt][rr];
        u32* yo = (u32*)y + ((size_t)(b * CT + rowbase + it * 16)) * (CD / 2) + h * 32;
#pragma unroll
        for (int p = 0; p < 8; p++) {
            const int idx = p * 64 + lane;
            const int row = idx >> 5, c2 = idx & 31;
            const float f0 = Ys[wave][row][2 * c2];
            const float f1 = Ys[wave][row][2 * c2 + 1];
            yo[(size_t)row * (CD / 2) + c2] = (u32)f2b(f0) | ((u32)f2b(f1) << 16);
        }
    }
}

// ---------------------------------------------------------------- emb pipeline
__global__ __launch_bounds__(256) void embsilu_kernel(const float* __restrict__ emb,
        float* __restrict__ se)
{
    const int i = blockIdx.x * 256 + threadIdx.x;
    if (i < CB * CTE) {
        const float e = emb[i];
        se[i] = e / (1.0f + __expf(-e));
    }
}
__global__ __launch_bounds__(256) void eoinit_kernel(const float* __restrict__ embB,
        float* __restrict__ eo)
{
    const int i = blockIdx.x * 256 + threadIdx.x;
    if (i < CB * CD2) eo[i] = embB[i & (CD2 - 1)];
}
__global__ __launch_bounds__(256) void embout2_kernel(const float* __restrict__ se,
        const float* __restrict__ embW, float* __restrict__ eo)
{
    const int jg = blockIdx.x & 15, kc = blockIdx.x >> 4;
    const int tid = threadIdx.x;
    const int jl = tid & 63, kgrp = tid >> 6;
    const int j = jg * 64 + jl;
    const int kbase = kc * 256 + kgrp * 64;
    const float* W = embW + (size_t)kbase * CD2 + j;
    const float* s0 = se + kbase;
    const float* s1 = s0 + CTE;
    const float* s2 = s1 + CTE;
    const float* s3 = s2 + CTE;
    float a0 = 0.0f, a1 = 0.0f, a2 = 0.0f, a3 = 0.0f;
#pragma unroll 8
    for (int kk = 0; kk < 64; kk++) {
        const float w = W[(size_t)kk * CD2];
        a0 = fmaf(s0[kk], w, a0);
        a1 = fmaf(s1[kk], w, a1);
        a2 = fmaf(s2[kk], w, a2);
        a3 = fmaf(s3[kk], w, a3);
    }
    __shared__ float red[4][4][64];   // [kgrp][b][j]
    red[kgrp][0][jl] = a0; red[kgrp][1][jl] = a1;
    red[kgrp][2][jl] = a2; red[kgrp][3][jl] = a3;
    __syncthreads();
    if (tid < 64) {
#pragma unroll
        for (int b = 0; b < 4; b++) {
            const float t = red[0][b][tid] + red[1][b][tid]
                          + red[2][b][tid] + red[3][b][tid];
            atomicAdd(&eo[(size_t)b * CD2 + jg * 64 + tid], t);
        }
    }
}

// ---------------------------------------------------------------- LN2 + stylization + silu: y bf16 -> s bf16
__global__ __launch_bounds__(256) void ln2_style_kernel(const u16* __restrict__ y,
        const float* __restrict__ g2, const float* __restrict__ bt2,
        const float* __restrict__ eo, u16* __restrict__ sout)
{
    const int row = blockIdx.x;
    const int tid = threadIdx.x;
    const int b = row >> 13;
    const u32 p = ((const u32*)(y + (size_t)row * CD))[tid];
    const float x0 = b2f((u16)(p & 0xffff));
    const float x1 = b2f((u16)(p >> 16));
    float s = x0 + x1;
    float sq = x0 * x0 + x1 * x1;
#pragma unroll
    for (int m = 1; m < 64; m <<= 1) { s += __shfl_xor(s, m); sq += __shfl_xor(sq, m); }
    __shared__ float red[8];
    const int wid = tid >> 6;
    if ((tid & 63) == 0) { red[wid] = s; red[wid + 4] = sq; }
    __syncthreads();
    s = red[0] + red[1] + red[2] + red[3];
    sq = red[4] + red[5] + red[6] + red[7];
    const float mu = s * (1.0f / CD);
    float var = sq * (1.0f / CD) - mu * mu;
    var = fmaxf(var, 0.0f);
    const float rs = rsqrtf(var + 1e-5f);
    const float2 gv = ((const float2*)g2)[tid];
    const float2 bv = ((const float2*)bt2)[tid];
    const float2 sc = ((const float2*)(eo + (size_t)b * CD2))[tid];
    const float2 sh = ((const float2*)(eo + (size_t)b * CD2 + CD))[tid];
    float h0 = (x0 - mu) * rs * gv.x + bv.x;
    float h1 = (x1 - mu) * rs * gv.y + bv.y;
    h0 = h0 * (1.0f + sc.x) + sh.x;
    h1 = h1 * (1.0f + sc.y) + sh.y;
    const float s0 = h0 / (1.0f + __expf(-h0));
    const float s1 = h1 / (1.0f + __expf(-h1));
    ((u32*)(sout + (size_t)row * CD))[tid] = (u32)f2b(s0) | ((u32)f2b(s1) << 16);
}

// ----------------------------------------------------------------
// Buffers:
//  d_out (64 MB fp32 out) as scratch until final GEMM:
//    R0 [0,32M):  k bf16 -> q bf16 (k dead after attn_kernel)
//    R1 [32M,64M): pm/ps (512 KB, dead before v-GEMM) -> v bf16 -> y bf16
//  d_ws (~36.4 MB used):
//    ws+0        : xn bf16 (32 MB) -> s bf16
//    ws+33554432 : Wt bf16 x4 [n][k]: Wk,Wv,Wq,outW (2 MB)
//    ws+35651584 : attn (512 KB fp32)
//    ws+36306944 : eo (16 KB fp32)
//    ws+36323328 : se (32 KB fp32, silu(emb))
extern "C" void kernel_launch(void* const* d_in, const int* in_sizes, int n_in,
                              void* d_out, int out_size, void* d_ws, size_t ws_size,
                              hipStream_t stream) {
    (void)in_sizes; (void)n_in; (void)out_size; (void)ws_size;
    const float* x    = (const float*)d_in[0];
    const float* emb  = (const float*)d_in[1];
    const float* mask = (const float*)d_in[2];
    const float* gamma= (const float*)d_in[3];
    const float* beta = (const float*)d_in[4];
    const float* Wq   = (const float*)d_in[5];
    const float* bq   = (const float*)d_in[6];
    const float* Wk   = (const float*)d_in[7];
    const float* bk   = (const float*)d_in[8];
    const float* Wv   = (const float*)d_in[9];
    const float* bv   = (const float*)d_in[10];
    const float* embW = (const float*)d_in[11];
    const float* embB = (const float*)d_in[12];
    const float* g2   = (const float*)d_in[13];
    const float* bt2  = (const float*)d_in[14];
    const float* outW = (const float*)d_in[15];
    const float* outb = (const float*)d_in[16];

    char* od = (char*)d_out;
    u16* kq  = (u16*)od;                        // R0: k then q
    u16* vy  = (u16*)(od + 33554432);           // R1: v then y
    float* outp = (float*)d_out;
    float* pm   = (float*)(od + 33554432);      // R1 head, dead before v-GEMM
    float* ps   = (float*)(od + 33554432 + 262144);

    char* ws = (char*)d_ws;
    u16* xn   = (u16*)ws;                       // 32 MB, later s
    u16* WtK  = (u16*)(ws + 33554432);
    u16* WtV  = WtK + (size_t)CD * CD;
    u16* WtQ  = WtV + (size_t)CD * CD;
    u16* WtO  = WtQ + (size_t)CD * CD;
    float* attn = (float*)(ws + 35651584);
    float* eo   = (float*)(ws + 36306944);
    float* se   = (float*)(ws + 36323328);

    wconv_kernel<<<dim3(64, 4), 256, 0, stream>>>(Wk, Wv, Wq, outW, WtK);
    ln1_kernel<<<CB * CT, 256, 0, stream>>>(x, gamma, beta, xn);
    zero_kernel<<<512, 256, 0, stream>>>(attn, CB * CH * CDH * CDH);
    embsilu_kernel<<<32, 256, 0, stream>>>(emb, se);
    eoinit_kernel<<<16, 256, 0, stream>>>(embB, eo);
    embout2_kernel<<<128, 256, 0, stream>>>(se, embW, eo);
    gemm_mfma<<<1024, 256, 0, stream>>>(xn, WtK, bk, kq, mask, nullptr, 1);
    ksm_partial<<<128, 256, 0, stream>>>(kq, pm, ps);
    ksm_norm<<<128, 256, 0, stream>>>(kq, pm, ps);
    gemm_mfma<<<1024, 256, 0, stream>>>(xn, WtV, bv, vy, mask, nullptr, 2);
    attn_kernel<<<512, 256, 0, stream>>>(kq, vy, attn);
    // k, v dead -> q into R0, y into R1
    gemm_mfma<<<1024, 256, 0, stream>>>(xn, WtQ, bq, kq, nullptr, nullptr, 0);
    y_mfma<<<1024, 256, 0, stream>>>(kq, attn, vy);
    ln2_style_kernel<<<CB * CT, 256, 0, stream>>>(vy, g2, bt2, eo, xn /* s */);
    gemm_mfma<<<1024, 256, 0, stream>>>(xn /* s */, WtO, outb, outp, nullptr, x, 3);
}

// Round 3
// 473.383 us; speedup vs baseline: 1.6585x; 1.1155x over previous
//
#include <hip/hip_runtime.h>
#include <cstdint>
#include <cstddef>

typedef unsigned short u16;
typedef unsigned int u32;
typedef __attribute__((ext_vector_type(8))) short short8;   // 8 x bf16 (4 VGPRs)
typedef __attribute__((ext_vector_type(4))) float f32x4;    // MFMA accumulator

static constexpr int CB = 4;
static constexpr int CT = 8192;
static constexpr int CD = 512;
static constexpr int CH = 8;
static constexpr int CDH = 64;
static constexpr int CTE = 2048;
static constexpr int CD2 = 1024;

__device__ __forceinline__ float b2f(u16 u) {
    return __uint_as_float(((u32)u) << 16);
}
__device__ __forceinline__ u16 f2b(float f) {
    u32 i = __float_as_uint(f);
    i = i + 0x7fffu + ((i >> 16) & 1u);   // round-to-nearest-even
    return (u16)(i >> 16);
}

typedef const __attribute__((address_space(1))) void* gas_p;
typedef __attribute__((address_space(3))) void* las_p;
#define GLD16(g, l) __builtin_amdgcn_global_load_lds((gas_p)(g), (las_p)(l), 16, 0, 0)

// ---------------------------------------------------------------- zero
__global__ __launch_bounds__(256) void zero_kernel(float* __restrict__ p, int n) {
    int i = blockIdx.x * 256 + threadIdx.x;
    if (i < n) p[i] = 0.0f;
}

// ---------------------------------------------------------------- W[k][n] fp32 -> Wt[n][k] bf16, tiled transpose
// grid = dim3(64, 4): 8x8 tiles of 64x64 per matrix; block 256
__global__ __launch_bounds__(256) void wconv_kernel(
        const float* __restrict__ W0, const float* __restrict__ W1,
        const float* __restrict__ W2, const float* __restrict__ W3,
        u16* __restrict__ Wt)
{
    const float* W;
    switch (blockIdx.y) {
        case 0: W = W0; break;
        case 1: W = W1; break;
        case 2: W = W2; break;
        default: W = W3; break;
    }
    u16* o = Wt + (size_t)blockIdx.y * CD * CD;
    const int k0 = (blockIdx.x >> 3) * 64;
    const int n0 = (blockIdx.x & 7) * 64;
    const int tid = threadIdx.x;
    __shared__ u16 tile[64][65];
    const int nn = tid & 63, kq = tid >> 6;
#pragma unroll
    for (int i = 0; i < 16; i++) {
        const int kk = i * 4 + kq;
        tile[kk][nn] = f2b(W[(size_t)(k0 + kk) * CD + n0 + nn]);  // coalesced read
    }
    __syncthreads();
    const int kk2 = tid & 63, nq = tid >> 6;
#pragma unroll
    for (int i = 0; i < 16; i++) {
        const int nn2 = i * 4 + nq;
        o[(size_t)(n0 + nn2) * CD + k0 + kk2] = tile[kk2][nn2];   // coalesced write
    }
}

// ---------------------------------------------------------------- LN1: fp32 x -> bf16 xn
__global__ __launch_bounds__(256) void ln1_kernel(const float* __restrict__ x,
        const float* __restrict__ g, const float* __restrict__ bt,
        u16* __restrict__ xn)
{
    const int row = blockIdx.x;
    const int tid = threadIdx.x;
    const float2 p = ((const float2*)(x + (size_t)row * CD))[tid];
    float s = p.x + p.y;
    float sq = p.x * p.x + p.y * p.y;
#pragma unroll
    for (int m = 1; m < 64; m <<= 1) { s += __shfl_xor(s, m); sq += __shfl_xor(sq, m); }
    __shared__ float red[8];
    const int wid = tid >> 6;
    if ((tid & 63) == 0) { red[wid] = s; red[wid + 4] = sq; }
    __syncthreads();
    s = red[0] + red[1] + red[2] + red[3];
    sq = red[4] + red[5] + red[6] + red[7];
    const float mu = s * (1.0f / CD);
    float var = sq * (1.0f / CD) - mu * mu;
    var = fmaxf(var, 0.0f);
    const float rs = rsqrtf(var + 1e-5f);
    const float2 gv = ((const float2*)g)[tid];
    const float2 bv = ((const float2*)bt)[tid];
    const float y0 = (p.x - mu) * rs * gv.x + bv.x;
    const float y1 = (p.y - mu) * rs * gv.y + bv.y;
    ((u32*)(xn + (size_t)row * CD))[tid] = (u32)f2b(y0) | ((u32)f2b(y1) << 16);
}

// ---------------------------------------------------------------- MFMA GEMM
// C[M,N] = A[M,K]bf16 @ Bt[N,K]bf16^T + bias, M=32768, K=512.
// mode 0 (q): N=512, out bf16 | mode 3 (o): N=512, + xres, out fp32
// mode 4 (kv fused): N=1024; cols<512 -> k (+(1-mask)*-1e6) into Cv,
//                    cols>=512 -> v (*mask) into Cv2. Bt = WtK||WtV contiguous.
// Tile 128x128, BK=32. Depth-2 prefetch, 3 LDS buffers, counted vmcnt (T4),
// raw s_barrier (no vmcnt-0 drain in loop). Bank-conflict-free via pre-swizzled
// global source + matching read swizzle (rule #21; slot s at row r holds
// global slot s ^ ((r>>1)&3)). XCD-aware block swizzle (T1).
__global__ __launch_bounds__(256) void gemm_mfma(
    const u16* __restrict__ A, const u16* __restrict__ Bt,
    const float* __restrict__ bias, const float* __restrict__ bias2,
    void* __restrict__ Cv, void* __restrict__ Cv2,
    const float* __restrict__ mask, const float* __restrict__ xres,
    int mode)
{
    __shared__ u16 As[3][128][32];   // 24 KB
    __shared__ u16 Bs[3][128][32];   // 24 KB
    const int tid = threadIdx.x;
    const int wave = tid >> 6, lane = tid & 63;
    const int quad = lane >> 4, l16 = lane & 15;

    const int n = blockIdx.x;
    const int xcd = n & 7;
    int by, bx;
    if (mode == 4) { const int slot = n >> 3; by = xcd * 32 + (slot >> 3); bx = slot & 7; }
    else           { const int slot = n >> 3; by = xcd * 32 + (slot >> 2); bx = slot & 3; }
    const int row0 = by * 128;
    const int col0 = bx * 128;
    const int wm = (wave >> 1) * 64, wn = (wave & 1) * 64;

    // mode-4 per-block specialization (col0 is 128-aligned, so side is uniform)
    int emode = mode;
    const float* bptr = bias;
    void* cout = Cv;
    int ocol0 = col0;
    if (mode == 4) {
        if (col0 >= 512) { emode = 2; bptr = bias2; cout = Cv2; ocol0 = col0 - 512; }
        else emode = 1;
    }

    f32x4 acc[4][4];
#pragma unroll
    for (int mt = 0; mt < 4; mt++)
#pragma unroll
        for (int nt = 0; nt < 4; nt++)
            acc[mt][nt] = (f32x4){0.0f, 0.0f, 0.0f, 0.0f};

    // staging: wave w stages rows [w*16, +16) and [w*16+64, +16) of A and B.
    // linear LDS dest = rowblock base + lane*16; source slot pre-swizzled.
    const int srow = lane >> 2;          // 0..15
    const int sslot = lane & 3;          // 16B slot
    const int swz = (srow >> 1) & 3;
    const int aw0 = wave * 16;
    const u16* gA0 = A + (size_t)(row0 + aw0 + srow) * CD + (sslot ^ swz) * 8;
    const u16* gA1 = gA0 + (size_t)64 * CD;
    const u16* gB0 = Bt + (size_t)(col0 + aw0 + srow) * CD + (sslot ^ swz) * 8;
    const u16* gB1 = gB0 + (size_t)64 * CD;

#define STAGE_T(bf, kt) do { \
        GLD16(gA0 + (kt) * 32, &As[bf][aw0][0]); \
        GLD16(gA1 + (kt) * 32, &As[bf][aw0 + 64][0]); \
        GLD16(gB0 + (kt) * 32, &Bs[bf][aw0][0]); \
        GLD16(gB1 + (kt) * 32, &Bs[bf][aw0 + 64][0]); \
    } while (0)

    STAGE_T(0, 0);
    STAGE_T(1, 1);

    const int swsel = (quad ^ ((l16 >> 1) & 3)) * 8;   // read-side swizzle

#pragma unroll
    for (int t = 0; t < 16; ++t) {
        const int bf = t % 3;
        if (t < 14) STAGE_T((t + 2) % 3, t + 2);
        // wait own tile-t loads (counted, never 0 mid-loop) + join
        if (t < 14)       asm volatile("s_waitcnt vmcnt(8)\ns_barrier" ::: "memory");
        else if (t == 14) asm volatile("s_waitcnt vmcnt(4)\ns_barrier" ::: "memory");
        else              asm volatile("s_waitcnt vmcnt(0)\ns_barrier" ::: "memory");

        short8 af[4], bfr[4];
#pragma unroll
        for (int mt = 0; mt < 4; mt++)
            af[mt] = *(const short8*)&As[bf][wm + mt * 16 + l16][swsel];
#pragma unroll
        for (int nt = 0; nt < 4; nt++)
            bfr[nt] = *(const short8*)&Bs[bf][wn + nt * 16 + l16][swsel];
#pragma unroll
        for (int mt = 0; mt < 4; mt++)
#pragma unroll
            for (int nt = 0; nt < 4; nt++)
                acc[mt][nt] = __builtin_amdgcn_mfma_f32_16x16x32_bf16(
                    af[mt], bfr[nt], acc[mt][nt], 0, 0, 0);
        // all our LDS reads retired before anyone re-stages this buffer
        asm volatile("s_waitcnt lgkmcnt(0)\ns_barrier" ::: "memory");
    }
#undef STAGE_T

    if (emode == 3) {
        // direct fp32 stores (+xres): 4B/lane, 64B/quad-row, full sectors
#pragma unroll
        for (int mt = 0; mt < 4; mt++) {
            const int rbase = row0 + wm + mt * 16 + quad * 4;
#pragma unroll
            for (int r = 0; r < 4; r++) {
                const int row = rbase + r;
#pragma unroll
                for (int nt = 0; nt < 4; nt++) {
                    const int col = ocol0 + wn + nt * 16 + l16;
                    const float val = acc[mt][nt][r] + bptr[col];
                    ((float*)cout)[(size_t)row * CD + col] =
                        val + xres[(size_t)row * CD + col];
                }
            }
        }
    } else {
        // packed bf16 epilogue: stage 16x64 f32 strip in padded LDS (reuse As),
        // then write coalesced u32 rows (128B per 32 lanes -> full sectors).
        float* stg = ((float*)&As[0][0][0]) + wave * (16 * 65);
#pragma unroll
        for (int mt = 0; mt < 4; mt++) {
#pragma unroll
            for (int r = 0; r < 4; r++) {
                const int rr = quad * 4 + r;
                const int grow = row0 + wm + mt * 16 + rr;
                float mval = 0.0f;
                if (emode == 1 || emode == 2) mval = mask[grow];
#pragma unroll
                for (int nt = 0; nt < 4; nt++) {
                    const int ocol = ocol0 + wn + nt * 16 + l16;
                    float val = acc[mt][nt][r] + bptr[ocol];
                    if (emode == 1) val += (1.0f - mval) * -1000000.0f;
                    else if (emode == 2) val *= mval;
                    stg[rr * 65 + nt * 16 + l16] = val;
                }
            }
            u16* cbase = (u16*)cout + (size_t)(row0 + wm + mt * 16) * CD + ocol0 + wn;
#pragma unroll
            for (int i = 0; i < 8; i++) {
                const int rr = i * 2 + (lane >> 5);
                const int c2 = lane & 31;
                const float f0 = stg[rr * 65 + 2 * c2];
                const float f1 = stg[rr * 65 + 2 * c2 + 1];
                ((u32*)(cbase + (size_t)rr * CD))[c2] =
                    (u32)f2b(f0) | ((u32)f2b(f1) << 16);
            }
        }
    }
}

// ---------------------------------------------------------------- k softmax over T (row-coalesced)
// pass 1: per-chunk max/sum partials. grid = B(4)*chunks(32) = 128; block 256.
__global__ __launch_bounds__(256) void ksm_partial(const u16* __restrict__ k,
        float* __restrict__ pm, float* __restrict__ ps)
{
    const int bid = blockIdx.x;
    const int b = bid >> 5, ch = bid & 31;
    const int tid = threadIdx.x;
    const u32* base = (const u32*)(k + (size_t)b * CT * CD + (size_t)ch * 256 * CD) + tid;
    float m0 = -3.0e38f, m1 = -3.0e38f;
#pragma unroll 8
    for (int r = 0; r < 256; ++r) {
        const u32 p = base[(size_t)r * 256];
        m0 = fmaxf(m0, b2f((u16)(p & 0xffff)));
        m1 = fmaxf(m1, b2f((u16)(p >> 16)));
    }
    float s0 = 0.0f, s1 = 0.0f;
#pragma unroll 8
    for (int r = 0; r < 256; ++r) {
        const u32 p = base[(size_t)r * 256];   // L2-resident re-read
        s0 += __expf(b2f((u16)(p & 0xffff)) - m0);
        s1 += __expf(b2f((u16)(p >> 16)) - m1);
    }
    const int d0 = tid * 2;
    pm[((size_t)b * CD + d0) * 32 + ch] = m0;
    pm[((size_t)b * CD + d0 + 1) * 32 + ch] = m1;
    ps[((size_t)b * CD + d0) * 32 + ch] = s0;
    ps[((size_t)b * CD + d0 + 1) * 32 + ch] = s1;
}

// pass 2: combine partials + normalize in place. grid = 128; block 256.
__global__ __launch_bounds__(256) void ksm_norm(u16* __restrict__ k,
        const float* __restrict__ pm, const float* __restrict__ ps)
{
    const int bid = blockIdx.x;
    const int b = bid >> 5, ch = bid & 31;
    const int tid = threadIdx.x;
    const int d0 = tid * 2;
    const float* pm0 = pm + ((size_t)b * CD + d0) * 32;
    const float* pm1 = pm0 + 32;
    const float* ps0 = ps + ((size_t)b * CD + d0) * 32;
    const float* ps1 = ps0 + 32;
    float M0 = -3.0e38f, M1 = -3.0e38f;
#pragma unroll
    for (int c = 0; c < 32; ++c) { M0 = fmaxf(M0, pm0[c]); M1 = fmaxf(M1, pm1[c]); }
    float S0 = 0.0f, S1 = 0.0f;
#pragma unroll
    for (int c = 0; c < 32; ++c) {
        S0 += ps0[c] * __expf(pm0[c] - M0);
        S1 += ps1[c] * __expf(pm1[c] - M1);
    }
    const float R0 = 1.0f / S0, R1 = 1.0f / S1;
    u32* base = (u32*)(k + (size_t)b * CT * CD + (size_t)ch * 256 * CD) + tid;
#pragma unroll 4
    for (int r = 0; r < 256; ++r) {
        const u32 p = base[(size_t)r * 256];
        const float x0 = __expf(b2f((u16)(p & 0xffff)) - M0) * R0;
        const float x1 = __expf(b2f((u16)(p >> 16)) - M1) * R1;
        base[(size_t)r * 256] = (u32)f2b(x0) | ((u32)f2b(x1) << 16);
    }
}

// ---------------------------------------------------------------- attn = sum_t k (outer) v, per (b,h)
// grid = 32 (b,h) * 16 tchunks = 512; block 256
__global__ __launch_bounds__(256) void attn_kernel(const u16* __restrict__ k,
        const u16* __restrict__ v, float* __restrict__ attn)
{
    const int bid = blockIdx.x;
    const int bh = bid >> 4, ch = bid & 15;
    const int b = bh >> 3, h = bh & 7;
    const int tid = threadIdx.x;
    __shared__ u16 Ks[32][64], Vs[32][64];
    const int ti = tid >> 4, tj = tid & 15;
    const int d0 = ti * 4, l0 = tj * 4;
    const int trow = tid >> 3, cg8 = (tid & 7) * 8;
    float acc[4][4];
#pragma unroll
    for (int r = 0; r < 4; r++)
#pragma unroll
        for (int c = 0; c < 4; c++) acc[r][c] = 0.0f;

    for (int st = 0; st < 16; st++) {
        const int t0 = ch * 512 + st * 32;
        const size_t goff = ((size_t)(b * CT + t0 + trow)) * CD + h * 64 + cg8;
        const uint4 kv4 = *(const uint4*)(k + goff);
        const uint4 vv4 = *(const uint4*)(v + goff);
        __syncthreads();
        *(uint4*)&Ks[trow][cg8] = kv4;
        *(uint4*)&Vs[trow][cg8] = vv4;
        __syncthreads();
#pragma unroll
        for (int tt = 0; tt < 32; tt++) {
            const ushort4 ka = *(const ushort4*)&Ks[tt][d0];
            const ushort4 va = *(const ushort4*)&Vs[tt][l0];
            const float kr[4] = { b2f(ka.x), b2f(ka.y), b2f(ka.z), b2f(ka.w) };
            const float vr[4] = { b2f(va.x), b2f(va.y), b2f(va.z), b2f(va.w) };
#pragma unroll
            for (int r = 0; r < 4; r++)
#pragma unroll
                for (int c = 0; c < 4; c++)
                    acc[r][c] = fmaf(kr[r], vr[c], acc[r][c]);
        }
    }
    float* ab = attn + (size_t)bh * 64 * 64;
#pragma unroll
    for (int r = 0; r < 4; r++)
#pragma unroll
        for (int c = 0; c < 4; c++)
            atomicAdd(&ab[(d0 + r) * 64 + l0 + c], acc[r][c]);
}

// ---------------------------------------------------------------- y = softmax(q over Dh) @ attn  (MFMA)
// grid = 32 (b,h) * 32 rowchunks = 1024; block 256 (4 waves), each wave 64 rows.
__global__ __launch_bounds__(256) void y_mfma(const u16* __restrict__ q,
        const float* __restrict__ attn, u16* __restrict__ y)
{
    const int bid = blockIdx.x;
    const int bh = bid >> 5;          // 0..31
    const int chunk = bid & 31;       // 0..31
    const int b = bh >> 3, h = bh & 7;
    const int tid = threadIdx.x;
    const int wave = tid >> 6, lane = tid & 63;
    const int quad = lane >> 4, l16 = lane & 15;

    __shared__ u16 Bh[64][72];        // Bt layout: [col l][k d], +8 pad keeps b128 align
    __shared__ u16 Bl[64][72];
    __shared__ float Ys[4][16][65];   // per-wave epilogue staging, padded

    const float* ab = attn + (size_t)bh * 64 * 64;
#pragma unroll
    for (int i = 0; i < 16; i++) {
        const int idx = i * 256 + tid;
        const int d = idx >> 6, l = idx & 63;
        const float a = ab[idx];
        const u16 hi = f2b(a);
        Bh[l][d] = hi;
        Bl[l][d] = f2b(a - b2f(hi));
    }
    __syncthreads();

    short8 bhf[4][2], blf[4][2];
#pragma unroll
    for (int nt = 0; nt < 4; nt++)
#pragma unroll
        for (int ks = 0; ks < 2; ks++) {
            bhf[nt][ks] = *(const short8*)&Bh[nt * 16 + l16][ks * 32 + quad * 8];
            blf[nt][ks] = *(const short8*)&Bl[nt * 16 + l16][ks * 32 + quad * 8];
        }

    const int rowbase = chunk * 256 + wave * 64;            // within this batch
    const size_t qb = ((size_t)(b * CT + rowbase)) * CD + h * 64;

#pragma unroll
    for (int it = 0; it < 4; it++) {
        const u16* qp = q + qb + (size_t)(it * 16 + l16) * CD + quad * 8;
        const uint4 q0 = *(const uint4*)qp;
        const uint4 q1 = *(const uint4*)(qp + 32);
        float xv[16];
        const u32 qw[8] = { q0.x, q0.y, q0.z, q0.w, q1.x, q1.y, q1.z, q1.w };
#pragma unroll
        for (int j = 0; j < 8; j++) {
            xv[2 * j]     = b2f((u16)(qw[j] & 0xffff));
            xv[2 * j + 1] = b2f((u16)(qw[j] >> 16));
        }
        float m = xv[0];
#pragma unroll
        for (int j = 1; j < 16; j++) m = fmaxf(m, xv[j]);
        m = fmaxf(m, __shfl_xor(m, 16));
        m = fmaxf(m, __shfl_xor(m, 32));
        float s = 0.0f;
#pragma unroll
        for (int j = 0; j < 16; j++) { xv[j] = __expf(xv[j] - m); s += xv[j]; }
        s += __shfl_xor(s, 16);
        s += __shfl_xor(s, 32);
        const float rinv = 1.0f / s;
        short8 ah[2], al[2];
#pragma unroll
        for (int ks = 0; ks < 2; ks++)
#pragma unroll
            for (int j = 0; j < 8; j++) {
                const float v = xv[ks * 8 + j] * rinv;
                const u16 hi = f2b(v);
                ah[ks][j] = (short)hi;
                al[ks][j] = (short)f2b(v - b2f(hi));
            }

        f32x4 acc[4];
#pragma unroll
        for (int nt = 0; nt < 4; nt++) acc[nt] = (f32x4){0.f, 0.f, 0.f, 0.f};
#pragma unroll
        for (int nt = 0; nt < 4; nt++) {
            acc[nt] = __builtin_amdgcn_mfma_f32_16x16x32_bf16(ah[0], bhf[nt][0], acc[nt], 0, 0, 0);
            acc[nt] = __builtin_amdgcn_mfma_f32_16x16x32_bf16(ah[1], bhf[nt][1], acc[nt], 0, 0, 0);
            acc[nt] = __builtin_amdgcn_mfma_f32_16x16x32_bf16(ah[0], blf[nt][0], acc[nt], 0, 0, 0);
            acc[nt] = __builtin_amdgcn_mfma_f32_16x16x32_bf16(ah[1], blf[nt][1], acc[nt], 0, 0, 0);
            acc[nt] = __builtin_amdgcn_mfma_f32_16x16x32_bf16(al[0], bhf[nt][0], acc[nt], 0, 0, 0);
            acc[nt] = __builtin_amdgcn_mfma_f32_16x16x32_bf16(al[1], bhf[nt][1], acc[nt], 0, 0, 0);
        }

#pragma unroll
        for (int nt = 0; nt < 4; nt++)
#pragma unroll
            for (int rr = 0; rr < 4; rr++)
                Ys[wave][quad * 4 + rr][nt * 16 + l16] = acc[nt][rr];
        u32* yo = (u32*)y + ((size_t)(b * CT + rowbase + it * 16)) * (CD / 2) + h * 32;
#pragma unroll
        for (int p = 0; p < 8; p++) {
            const int idx = p * 64 + lane;
            const int row = idx >> 5, c2 = idx & 31;
            const float f0 = Ys[wave][row][2 * c2];
            const float f1 = Ys[wave][row][2 * c2 + 1];
            yo[(size_t)row * (CD / 2) + c2] = (u32)f2b(f0) | ((u32)f2b(f1) << 16);
        }
    }
}

// ---------------------------------------------------------------- emb pipeline
__global__ __launch_bounds__(256) void embsilu_kernel(const float* __restrict__ emb,
        float* __restrict__ se)
{
    const int i = blockIdx.x * 256 + threadIdx.x;
    if (i < CB * CTE) {
        const float e = emb[i];
        se[i] = e / (1.0f + __expf(-e));
    }
}
__global__ __launch_bounds__(256) void eoinit_kernel(const float* __restrict__ embB,
        float* __restrict__ eo)
{
    const int i = blockIdx.x * 256 + threadIdx.x;
    if (i < CB * CD2) eo[i] = embB[i & (CD2 - 1)];
}
__global__ __launch_bounds__(256) void embout2_kernel(const float* __restrict__ se,
        const float* __restrict__ embW, float* __restrict__ eo)
{
    const int jg = blockIdx.x & 15, kc = blockIdx.x >> 4;
    const int tid = threadIdx.x;
    const int jl = tid & 63, kgrp = tid >> 6;
    const int j = jg * 64 + jl;
    const int kbase = kc * 256 + kgrp * 64;
    const float* W = embW + (size_t)kbase * CD2 + j;
    const float* s0 = se + kbase;
    const float* s1 = s0 + CTE;
    const float* s2 = s1 + CTE;
    const float* s3 = s2 + CTE;
    float a0 = 0.0f, a1 = 0.0f, a2 = 0.0f, a3 = 0.0f;
#pragma unroll 8
    for (int kk = 0; kk < 64; kk++) {
        const float w = W[(size_t)kk * CD2];
        a0 = fmaf(s0[kk], w, a0);
        a1 = fmaf(s1[kk], w, a1);
        a2 = fmaf(s2[kk], w, a2);
        a3 = fmaf(s3[kk], w, a3);
    }
    __shared__ float red[4][4][64];   // [kgrp][b][j]
    red[kgrp][0][jl] = a0; red[kgrp][1][jl] = a1;
    red[kgrp][2][jl] = a2; red[kgrp][3][jl] = a3;
    __syncthreads();
    if (tid < 64) {
#pragma unroll
        for (int b = 0; b < 4; b++) {
            const float t = red[0][b][tid] + red[1][b][tid]
                          + red[2][b][tid] + red[3][b][tid];
            atomicAdd(&eo[(size_t)b * CD2 + jg * 64 + tid], t);
        }
    }
}

// ---------------------------------------------------------------- LN2 + stylization + silu: y bf16 -> s bf16
__global__ __launch_bounds__(256) void ln2_style_kernel(const u16* __restrict__ y,
        const float* __restrict__ g2, const float* __restrict__ bt2,
        const float* __restrict__ eo, u16* __restrict__ sout)
{
    const int row = blockIdx.x;
    const int tid = threadIdx.x;
    const int b = row >> 13;
    const u32 p = ((const u32*)(y + (size_t)row * CD))[tid];
    const float x0 = b2f((u16)(p & 0xffff));
    const float x1 = b2f((u16)(p >> 16));
    float s = x0 + x1;
    float sq = x0 * x0 + x1 * x1;
#pragma unroll
    for (int m = 1; m < 64; m <<= 1) { s += __shfl_xor(s, m); sq += __shfl_xor(sq, m); }
    __shared__ float red[8];
    const int wid = tid >> 6;
    if ((tid & 63) == 0) { red[wid] = s; red[wid + 4] = sq; }
    __syncthreads();
    s = red[0] + red[1] + red[2] + red[3];
    sq = red[4] + red[5] + red[6] + red[7];
    const float mu = s * (1.0f / CD);
    float var = sq * (1.0f / CD) - mu * mu;
    var = fmaxf(var, 0.0f);
    const float rs = rsqrtf(var + 1e-5f);
    const float2 gv = ((const float2*)g2)[tid];
    const float2 bv = ((const float2*)bt2)[tid];
    const float2 sc = ((const float2*)(eo + (size_t)b * CD2))[tid];
    const float2 sh = ((const float2*)(eo + (size_t)b * CD2 + CD))[tid];
    float h0 = (x0 - mu) * rs * gv.x + bv.x;
    float h1 = (x1 - mu) * rs * gv.y + bv.y;
    h0 = h0 * (1.0f + sc.x) + sh.x;
    h1 = h1 * (1.0f + sc.y) + sh.y;
    const float s0 = h0 / (1.0f + __expf(-h0));
    const float s1 = h1 / (1.0f + __expf(-h1));
    ((u32*)(sout + (size_t)row * CD))[tid] = (u32)f2b(s0) | ((u32)f2b(s1) << 16);
}

// ----------------------------------------------------------------
// Buffers:
//  d_out (64 MB fp32 out) as scratch until final GEMM:
//    R0 [0,32M):  k bf16 -> q bf16 (k dead after attn_kernel)
//    R1 [32M,64M): v bf16 -> y bf16
//  d_ws (~36.4 MB used):
//    ws+0        : xn bf16 (32 MB) -> s bf16
//    ws+33554432 : Wt bf16 x4 [n][k]: Wk,Wv,Wq,outW (2 MB)
//    ws+35651584 : pm/ps (512 KB, dead after ksm_norm) -> attn (512 KB fp32)
//    ws+36306944 : eo (16 KB fp32)
//    ws+36323328 : se (32 KB fp32, silu(emb))
extern "C" void kernel_launch(void* const* d_in, const int* in_sizes, int n_in,
                              void* d_out, int out_size, void* d_ws, size_t ws_size,
                              hipStream_t stream) {
    (void)in_sizes; (void)n_in; (void)out_size; (void)ws_size;
    const float* x    = (const float*)d_in[0];
    const float* emb  = (const float*)d_in[1];
    const float* mask = (const float*)d_in[2];
    const float* gamma= (const float*)d_in[3];
    const float* beta = (const float*)d_in[4];
    const float* Wq   = (const float*)d_in[5];
    const float* bq   = (const float*)d_in[6];
    const float* Wk   = (const float*)d_in[7];
    const float* bk   = (const float*)d_in[8];
    const float* Wv   = (const float*)d_in[9];
    const float* bv   = (const float*)d_in[10];
    const float* embW = (const float*)d_in[11];
    const float* embB = (const float*)d_in[12];
    const float* g2   = (const float*)d_in[13];
    const float* bt2  = (const float*)d_in[14];
    const float* outW = (const float*)d_in[15];
    const float* outb = (const float*)d_in[16];

    char* od = (char*)d_out;
    u16* kq  = (u16*)od;                        // R0: k then q
    u16* vy  = (u16*)(od + 33554432);           // R1: v then y
    float* outp = (float*)d_out;

    char* ws = (char*)d_ws;
    u16* xn   = (u16*)ws;                       // 32 MB, later s
    u16* WtK  = (u16*)(ws + 33554432);
    u16* WtV  = WtK + (size_t)CD * CD;
    u16* WtQ  = WtV + (size_t)CD * CD;
    u16* WtO  = WtQ + (size_t)CD * CD;
    float* pm   = (float*)(ws + 35651584);      // 256 KB
    float* ps   = (float*)(ws + 35651584 + 262144); // 256 KB
    float* attn = (float*)(ws + 35651584);      // reuses pm/ps region after ksm
    float* eo   = (float*)(ws + 36306944);
    float* se   = (float*)(ws + 36323328);

    wconv_kernel<<<dim3(64, 4), 256, 0, stream>>>(Wk, Wv, Wq, outW, WtK);
    ln1_kernel<<<CB * CT, 256, 0, stream>>>(x, gamma, beta, xn);
    embsilu_kernel<<<32, 256, 0, stream>>>(emb, se);
    eoinit_kernel<<<16, 256, 0, stream>>>(embB, eo);
    embout2_kernel<<<128, 256, 0, stream>>>(se, embW, eo);
    // fused k+v GEMM (mode 4): k -> kq, v -> vy
    gemm_mfma<<<2048, 256, 0, stream>>>(xn, WtK, bk, bv, kq, vy, mask, nullptr, 4);
    ksm_partial<<<128, 256, 0, stream>>>(kq, pm, ps);
    ksm_norm<<<128, 256, 0, stream>>>(kq, pm, ps);
    zero_kernel<<<512, 256, 0, stream>>>(attn, CB * CH * CDH * CDH);
    attn_kernel<<<512, 256, 0, stream>>>(kq, vy, attn);
    // k, v dead -> q into R0, y into R1
    gemm_mfma<<<1024, 256, 0, stream>>>(xn, WtQ, bq, nullptr, kq, nullptr, nullptr, nullptr, 0);
    y_mfma<<<1024, 256, 0, stream>>>(kq, attn, vy);
    ln2_style_kernel<<<CB * CT, 256, 0, stream>>>(vy, g2, bt2, eo, xn /* s */);
    gemm_mfma<<<1024, 256, 0, stream>>>(xn /* s */, WtO, outb, nullptr, outp, nullptr, nullptr, x, 3);
}

// Round 4
// 471.882 us; speedup vs baseline: 1.6638x; 1.0032x over previous
//
#include <hip/hip_runtime.h>
#include <cstdint>
#include <cstddef>

typedef unsigned short u16;
typedef unsigned int u32;
typedef __attribute__((ext_vector_type(8))) short short8;   // 8 x bf16 (4 VGPRs)
typedef __attribute__((ext_vector_type(4))) float f32x4;    // MFMA accumulator

static constexpr int CB = 4;
static constexpr int CT = 8192;
static constexpr int CD = 512;
static constexpr int CH = 8;
static constexpr int CDH = 64;
static constexpr int CTE = 2048;
static constexpr int CD2 = 1024;

__device__ __forceinline__ float b2f(u16 u) {
    return __uint_as_float(((u32)u) << 16);
}
__device__ __forceinline__ u16 f2b(float f) {
    u32 i = __float_as_uint(f);
    i = i + 0x7fffu + ((i >> 16) & 1u);   // round-to-nearest-even
    return (u16)(i >> 16);
}

typedef const __attribute__((address_space(1))) void* gas_p;
typedef __attribute__((address_space(3))) void* las_p;
#define GLD16(g, l) __builtin_amdgcn_global_load_lds((gas_p)(g), (las_p)(l), 16, 0, 0)

// ---------------------------------------------------------------- zero
__global__ __launch_bounds__(256) void zero_kernel(float* __restrict__ p, int n) {
    int i = blockIdx.x * 256 + threadIdx.x;
    if (i < n) p[i] = 0.0f;
}

// ---------------------------------------------------------------- W[k][n] fp32 -> Wt[n][k] bf16, tiled transpose
// grid = dim3(64, 4): 8x8 tiles of 64x64 per matrix; block 256
__global__ __launch_bounds__(256) void wconv_kernel(
        const float* __restrict__ W0, const float* __restrict__ W1,
        const float* __restrict__ W2, const float* __restrict__ W3,
        u16* __restrict__ Wt)
{
    const float* W;
    switch (blockIdx.y) {
        case 0: W = W0; break;
        case 1: W = W1; break;
        case 2: W = W2; break;
        default: W = W3; break;
    }
    u16* o = Wt + (size_t)blockIdx.y * CD * CD;
    const int k0 = (blockIdx.x >> 3) * 64;
    const int n0 = (blockIdx.x & 7) * 64;
    const int tid = threadIdx.x;
    __shared__ u16 tile[64][65];
    const int nn = tid & 63, kq = tid >> 6;
#pragma unroll
    for (int i = 0; i < 16; i++) {
        const int kk = i * 4 + kq;
        tile[kk][nn] = f2b(W[(size_t)(k0 + kk) * CD + n0 + nn]);  // coalesced read
    }
    __syncthreads();
    const int kk2 = tid & 63, nq = tid >> 6;
#pragma unroll
    for (int i = 0; i < 16; i++) {
        const int nn2 = i * 4 + nq;
        o[(size_t)(n0 + nn2) * CD + k0 + kk2] = tile[kk2][nn2];   // coalesced write
    }
}

// ---------------------------------------------------------------- LN1: fp32 x -> bf16 xn
__global__ __launch_bounds__(256) void ln1_kernel(const float* __restrict__ x,
        const float* __restrict__ g, const float* __restrict__ bt,
        u16* __restrict__ xn)
{
    const int row = blockIdx.x;
    const int tid = threadIdx.x;
    const float2 p = ((const float2*)(x + (size_t)row * CD))[tid];
    float s = p.x + p.y;
    float sq = p.x * p.x + p.y * p.y;
#pragma unroll
    for (int m = 1; m < 64; m <<= 1) { s += __shfl_xor(s, m); sq += __shfl_xor(sq, m); }
    __shared__ float red[8];
    const int wid = tid >> 6;
    if ((tid & 63) == 0) { red[wid] = s; red[wid + 4] = sq; }
    __syncthreads();
    s = red[0] + red[1] + red[2] + red[3];
    sq = red[4] + red[5] + red[6] + red[7];
    const float mu = s * (1.0f / CD);
    float var = sq * (1.0f / CD) - mu * mu;
    var = fmaxf(var, 0.0f);
    const float rs = rsqrtf(var + 1e-5f);
    const float2 gv = ((const float2*)g)[tid];
    const float2 bv = ((const float2*)bt)[tid];
    const float y0 = (p.x - mu) * rs * gv.x + bv.x;
    const float y1 = (p.y - mu) * rs * gv.y + bv.y;
    ((u32*)(xn + (size_t)row * CD))[tid] = (u32)f2b(y0) | ((u32)f2b(y1) << 16);
}

// ---------------------------------------------------------------- MFMA GEMM
// C[M,N] = A[M,K]bf16 @ Bt[N,K]bf16^T + bias, M=32768, K=512.
// mode 0 (q): N=512, out bf16 | mode 3 (o): N=512, + xres, out fp32
// mode 4 (kv fused): N=1024; cols<512 -> k (+(1-mask)*-1e6) into Cv,
//                    cols>=512 -> v (*mask) into Cv2. Bt = WtK||WtV contiguous.
// Tile 128x128, BK=32. 2 LDS buffers (32 KB -> 4-5 blocks/CU), depth-1
// prefetch with counted vmcnt(4) (T4: never drain to 0 mid-loop), raw
// s_barrier, setprio around MFMA cluster (T5). Bank-conflict-free via
// pre-swizzled global source + matching read swizzle (rule #21).
// XCD-aware block swizzle (T1).
__global__ __launch_bounds__(256) void gemm_mfma(
    const u16* __restrict__ A, const u16* __restrict__ Bt,
    const float* __restrict__ bias, const float* __restrict__ bias2,
    void* __restrict__ Cv, void* __restrict__ Cv2,
    const float* __restrict__ mask, const float* __restrict__ xres,
    int mode)
{
    __shared__ u16 As[2][128][32];   // 16 KB
    __shared__ u16 Bs[2][128][32];   // 16 KB
    const int tid = threadIdx.x;
    const int wave = tid >> 6, lane = tid & 63;
    const int quad = lane >> 4, l16 = lane & 15;

    const int n = blockIdx.x;
    const int xcd = n & 7;
    int by, bx;
    if (mode == 4) { const int slot = n >> 3; by = xcd * 32 + (slot >> 3); bx = slot & 7; }
    else           { const int slot = n >> 3; by = xcd * 32 + (slot >> 2); bx = slot & 3; }
    const int row0 = by * 128;
    const int col0 = bx * 128;
    const int wm = (wave >> 1) * 64, wn = (wave & 1) * 64;

    // mode-4 per-block specialization (col0 is 128-aligned, so side is uniform)
    int emode = mode;
    const float* bptr = bias;
    void* cout = Cv;
    int ocol0 = col0;
    if (mode == 4) {
        if (col0 >= 512) { emode = 2; bptr = bias2; cout = Cv2; ocol0 = col0 - 512; }
        else emode = 1;
    }

    f32x4 acc[4][4];
#pragma unroll
    for (int mt = 0; mt < 4; mt++)
#pragma unroll
        for (int nt = 0; nt < 4; nt++)
            acc[mt][nt] = (f32x4){0.0f, 0.0f, 0.0f, 0.0f};

    // staging: wave w stages rows [w*16, +16) and [w*16+64, +16) of A and B.
    // linear LDS dest = rowblock base + lane*16; source slot pre-swizzled.
    const int srow = lane >> 2;          // 0..15
    const int sslot = lane & 3;          // 16B slot
    const int swz = (srow >> 1) & 3;
    const int aw0 = wave * 16;
    const u16* gA0 = A + (size_t)(row0 + aw0 + srow) * CD + (sslot ^ swz) * 8;
    const u16* gA1 = gA0 + (size_t)64 * CD;
    const u16* gB0 = Bt + (size_t)(col0 + aw0 + srow) * CD + (sslot ^ swz) * 8;
    const u16* gB1 = gB0 + (size_t)64 * CD;

#define STAGE_T(bf, kt) do { \
        GLD16(gA0 + (kt) * 32, &As[bf][aw0][0]); \
        GLD16(gA1 + (kt) * 32, &As[bf][aw0 + 64][0]); \
        GLD16(gB0 + (kt) * 32, &Bs[bf][aw0][0]); \
        GLD16(gB1 + (kt) * 32, &Bs[bf][aw0 + 64][0]); \
    } while (0)

    STAGE_T(0, 0);

    const int swsel = (quad ^ ((l16 >> 1) & 3)) * 8;   // read-side swizzle

#pragma unroll
    for (int t = 0; t < 16; ++t) {
        const int bf = t & 1;
        if (t < 15) STAGE_T(bf ^ 1, t + 1);
        // wait own tile-t loads (counted, never 0 mid-loop) + join.
        // prev-iter's lgkmcnt(0)+barrier guarantees buffer bf's readers done.
        if (t < 15) asm volatile("s_waitcnt vmcnt(4)\ns_barrier" ::: "memory");
        else        asm volatile("s_waitcnt vmcnt(0)\ns_barrier" ::: "memory");

        short8 af[4], bfr[4];
#pragma unroll
        for (int mt = 0; mt < 4; mt++)
            af[mt] = *(const short8*)&As[bf][wm + mt * 16 + l16][swsel];
#pragma unroll
        for (int nt = 0; nt < 4; nt++)
            bfr[nt] = *(const short8*)&Bs[bf][wn + nt * 16 + l16][swsel];
        __builtin_amdgcn_s_setprio(1);
#pragma unroll
        for (int mt = 0; mt < 4; mt++)
#pragma unroll
            for (int nt = 0; nt < 4; nt++)
                acc[mt][nt] = __builtin_amdgcn_mfma_f32_16x16x32_bf16(
                    af[mt], bfr[nt], acc[mt][nt], 0, 0, 0);
        __builtin_amdgcn_s_setprio(0);
        // all our LDS reads retired before anyone re-stages this buffer
        asm volatile("s_waitcnt lgkmcnt(0)\ns_barrier" ::: "memory");
    }
#undef STAGE_T

    if (emode == 3) {
        // direct fp32 stores (+xres): 4B/lane, 64B/quad-row, full sectors
#pragma unroll
        for (int mt = 0; mt < 4; mt++) {
            const int rbase = row0 + wm + mt * 16 + quad * 4;
#pragma unroll
            for (int r = 0; r < 4; r++) {
                const int row = rbase + r;
#pragma unroll
                for (int nt = 0; nt < 4; nt++) {
                    const int col = ocol0 + wn + nt * 16 + l16;
                    const float val = acc[mt][nt][r] + bptr[col];
                    ((float*)cout)[(size_t)row * CD + col] =
                        val + xres[(size_t)row * CD + col];
                }
            }
        }
    } else {
        // packed bf16 epilogue: stage 16x64 f32 strip in padded LDS (reuse
        // As for waves 0-1, Bs for waves 2-3), then coalesced u32 row writes.
        float* stg = (wave < 2 ? (float*)&As[0][0][0] : (float*)&Bs[0][0][0])
                   + (wave & 1) * (16 * 65);
#pragma unroll
        for (int mt = 0; mt < 4; mt++) {
#pragma unroll
            for (int r = 0; r < 4; r++) {
                const int rr = quad * 4 + r;
                const int grow = row0 + wm + mt * 16 + rr;
                float mval = 0.0f;
                if (emode == 1 || emode == 2) mval = mask[grow];
#pragma unroll
                for (int nt = 0; nt < 4; nt++) {
                    const int ocol = ocol0 + wn + nt * 16 + l16;
                    float val = acc[mt][nt][r] + bptr[ocol];
                    if (emode == 1) val += (1.0f - mval) * -1000000.0f;
                    else if (emode == 2) val *= mval;
                    stg[rr * 65 + nt * 16 + l16] = val;
                }
            }
            u16* cbase = (u16*)cout + (size_t)(row0 + wm + mt * 16) * CD + ocol0 + wn;
#pragma unroll
            for (int i = 0; i < 8; i++) {
                const int rr = i * 2 + (lane >> 5);
                const int c2 = lane & 31;
                const float f0 = stg[rr * 65 + 2 * c2];
                const float f1 = stg[rr * 65 + 2 * c2 + 1];
                ((u32*)(cbase + (size_t)rr * CD))[c2] =
                    (u32)f2b(f0) | ((u32)f2b(f1) << 16);
            }
        }
    }
}

// ---------------------------------------------------------------- k softmax over T (row-coalesced)
// pass 1: per-chunk max/sum partials. grid = B(4)*chunks(32) = 128; block 256.
__global__ __launch_bounds__(256) void ksm_partial(const u16* __restrict__ k,
        float* __restrict__ pm, float* __restrict__ ps)
{
    const int bid = blockIdx.x;
    const int b = bid >> 5, ch = bid & 31;
    const int tid = threadIdx.x;
    const u32* base = (const u32*)(k + (size_t)b * CT * CD + (size_t)ch * 256 * CD) + tid;
    float m0 = -3.0e38f, m1 = -3.0e38f;
#pragma unroll 8
    for (int r = 0; r < 256; ++r) {
        const u32 p = base[(size_t)r * 256];
        m0 = fmaxf(m0, b2f((u16)(p & 0xffff)));
        m1 = fmaxf(m1, b2f((u16)(p >> 16)));
    }
    float s0 = 0.0f, s1 = 0.0f;
#pragma unroll 8
    for (int r = 0; r < 256; ++r) {
        const u32 p = base[(size_t)r * 256];   // L2-resident re-read
        s0 += __expf(b2f((u16)(p & 0xffff)) - m0);
        s1 += __expf(b2f((u16)(p >> 16)) - m1);
    }
    const int d0 = tid * 2;
    pm[((size_t)b * CD + d0) * 32 + ch] = m0;
    pm[((size_t)b * CD + d0 + 1) * 32 + ch] = m1;
    ps[((size_t)b * CD + d0) * 32 + ch] = s0;
    ps[((size_t)b * CD + d0 + 1) * 32 + ch] = s1;
}

// pass 2: combine partials + normalize in place. grid = 128; block 256.
__global__ __launch_bounds__(256) void ksm_norm(u16* __restrict__ k,
        const float* __restrict__ pm, const float* __restrict__ ps)
{
    const int bid = blockIdx.x;
    const int b = bid >> 5, ch = bid & 31;
    const int tid = threadIdx.x;
    const int d0 = tid * 2;
    const float* pm0 = pm + ((size_t)b * CD + d0) * 32;
    const float* pm1 = pm0 + 32;
    const float* ps0 = ps + ((size_t)b * CD + d0) * 32;
    const float* ps1 = ps0 + 32;
    float M0 = -3.0e38f, M1 = -3.0e38f;
#pragma unroll
    for (int c = 0; c < 32; ++c) { M0 = fmaxf(M0, pm0[c]); M1 = fmaxf(M1, pm1[c]); }
    float S0 = 0.0f, S1 = 0.0f;
#pragma unroll
    for (int c = 0; c < 32; ++c) {
        S0 += ps0[c] * __expf(pm0[c] - M0);
        S1 += ps1[c] * __expf(pm1[c] - M1);
    }
    const float R0 = 1.0f / S0, R1 = 1.0f / S1;
    u32* base = (u32*)(k + (size_t)b * CT * CD + (size_t)ch * 256 * CD) + tid;
#pragma unroll 4
    for (int r = 0; r < 256; ++r) {
        const u32 p = base[(size_t)r * 256];
        const float x0 = __expf(b2f((u16)(p & 0xffff)) - M0) * R0;
        const float x1 = __expf(b2f((u16)(p >> 16)) - M1) * R1;
        base[(size_t)r * 256] = (u32)f2b(x0) | ((u32)f2b(x1) << 16);
    }
}

// ---------------------------------------------------------------- attn = sum_t k (outer) v, per (b,h)
// grid = 32 (b,h) * 16 tchunks = 512; block 256
__global__ __launch_bounds__(256) void attn_kernel(const u16* __restrict__ k,
        const u16* __restrict__ v, float* __restrict__ attn)
{
    const int bid = blockIdx.x;
    const int bh = bid >> 4, ch = bid & 15;
    const int b = bh >> 3, h = bh & 7;
    const int tid = threadIdx.x;
    __shared__ u16 Ks[32][64], Vs[32][64];
    const int ti = tid >> 4, tj = tid & 15;
    const int d0 = ti * 4, l0 = tj * 4;
    const int trow = tid >> 3, cg8 = (tid & 7) * 8;
    float acc[4][4];
#pragma unroll
    for (int r = 0; r < 4; r++)
#pragma unroll
        for (int c = 0; c < 4; c++) acc[r][c] = 0.0f;

    for (int st = 0; st < 16; st++) {
        const int t0 = ch * 512 + st * 32;
        const size_t goff = ((size_t)(b * CT + t0 + trow)) * CD + h * 64 + cg8;
        const uint4 kv4 = *(const uint4*)(k + goff);
        const uint4 vv4 = *(const uint4*)(v + goff);
        __syncthreads();
        *(uint4*)&Ks[trow][cg8] = kv4;
        *(uint4*)&Vs[trow][cg8] = vv4;
        __syncthreads();
#pragma unroll
        for (int tt = 0; tt < 32; tt++) {
            const ushort4 ka = *(const ushort4*)&Ks[tt][d0];
            const ushort4 va = *(const ushort4*)&Vs[tt][l0];
            const float kr[4] = { b2f(ka.x), b2f(ka.y), b2f(ka.z), b2f(ka.w) };
            const float vr[4] = { b2f(va.x), b2f(va.y), b2f(va.z), b2f(va.w) };
#pragma unroll
            for (int r = 0; r < 4; r++)
#pragma unroll
                for (int c = 0; c < 4; c++)
                    acc[r][c] = fmaf(kr[r], vr[c], acc[r][c]);
        }
    }
    float* ab = attn + (size_t)bh * 64 * 64;
#pragma unroll
    for (int r = 0; r < 4; r++)
#pragma unroll
        for (int c = 0; c < 4; c++)
            atomicAdd(&ab[(d0 + r) * 64 + l0 + c], acc[r][c]);
}

// ---------------------------------------------------------------- y = softmax(q over Dh) @ attn  (MFMA)
// grid = 32 (b,h) * 32 rowchunks = 1024; block 256 (4 waves), each wave 64 rows.
__global__ __launch_bounds__(256) void y_mfma(const u16* __restrict__ q,
        const float* __restrict__ attn, u16* __restrict__ y)
{
    const int bid = blockIdx.x;
    const int bh = bid >> 5;          // 0..31
    const int chunk = bid & 31;       // 0..31
    const int b = bh >> 3, h = bh & 7;
    const int tid = threadIdx.x;
    const int wave = tid >> 6, lane = tid & 63;
    const int quad = lane >> 4, l16 = lane & 15;

    __shared__ u16 Bh[64][72];        // Bt layout: [col l][k d], +8 pad keeps b128 align
    __shared__ u16 Bl[64][72];
    __shared__ float Ys[4][16][65];   // per-wave epilogue staging, padded

    const float* ab = attn + (size_t)bh * 64 * 64;
#pragma unroll
    for (int i = 0; i < 16; i++) {
        const int idx = i * 256 + tid;
        const int d = idx >> 6, l = idx & 63;
        const float a = ab[idx];
        const u16 hi = f2b(a);
        Bh[l][d] = hi;
        Bl[l][d] = f2b(a - b2f(hi));
    }
    __syncthreads();

    short8 bhf[4][2], blf[4][2];
#pragma unroll
    for (int nt = 0; nt < 4; nt++)
#pragma unroll
        for (int ks = 0; ks < 2; ks++) {
            bhf[nt][ks] = *(const short8*)&Bh[nt * 16 + l16][ks * 32 + quad * 8];
            blf[nt][ks] = *(const short8*)&Bl[nt * 16 + l16][ks * 32 + quad * 8];
        }

    const int rowbase = chunk * 256 + wave * 64;            // within this batch
    const size_t qb = ((size_t)(b * CT + rowbase)) * CD + h * 64;

#pragma unroll
    for (int it = 0; it < 4; it++) {
        const u16* qp = q + qb + (size_t)(it * 16 + l16) * CD + quad * 8;
        const uint4 q0 = *(const uint4*)qp;
        const uint4 q1 = *(const uint4*)(qp + 32);
        float xv[16];
        const u32 qw[8] = { q0.x, q0.y, q0.z, q0.w, q1.x, q1.y, q1.z, q1.w };
#pragma unroll
        for (int j = 0; j < 8; j++) {
            xv[2 * j]     = b2f((u16)(qw[j] & 0xffff));
            xv[2 * j + 1] = b2f((u16)(qw[j] >> 16));
        }
        float m = xv[0];
#pragma unroll
        for (int j = 1; j < 16; j++) m = fmaxf(m, xv[j]);
        m = fmaxf(m, __shfl_xor(m, 16));
        m = fmaxf(m, __shfl_xor(m, 32));
        float s = 0.0f;
#pragma unroll
        for (int j = 0; j < 16; j++) { xv[j] = __expf(xv[j] - m); s += xv[j]; }
        s += __shfl_xor(s, 16);
        s += __shfl_xor(s, 32);
        const float rinv = 1.0f / s;
        short8 ah[2], al[2];
#pragma unroll
        for (int ks = 0; ks < 2; ks++)
#pragma unroll
            for (int j = 0; j < 8; j++) {
                const float v = xv[ks * 8 + j] * rinv;
                const u16 hi = f2b(v);
                ah[ks][j] = (short)hi;
                al[ks][j] = (short)f2b(v - b2f(hi));
            }

        f32x4 acc[4];
#pragma unroll
        for (int nt = 0; nt < 4; nt++) acc[nt] = (f32x4){0.f, 0.f, 0.f, 0.f};
#pragma unroll
        for (int nt = 0; nt < 4; nt++) {
            acc[nt] = __builtin_amdgcn_mfma_f32_16x16x32_bf16(ah[0], bhf[nt][0], acc[nt], 0, 0, 0);
            acc[nt] = __builtin_amdgcn_mfma_f32_16x16x32_bf16(ah[1], bhf[nt][1], acc[nt], 0, 0, 0);
            acc[nt] = __builtin_amdgcn_mfma_f32_16x16x32_bf16(ah[0], blf[nt][0], acc[nt], 0, 0, 0);
            acc[nt] = __builtin_amdgcn_mfma_f32_16x16x32_bf16(ah[1], blf[nt][1], acc[nt], 0, 0, 0);
            acc[nt] = __builtin_amdgcn_mfma_f32_16x16x32_bf16(al[0], bhf[nt][0], acc[nt], 0, 0, 0);
            acc[nt] = __builtin_amdgcn_mfma_f32_16x16x32_bf16(al[1], bhf[nt][1], acc[nt], 0, 0, 0);
        }

#pragma unroll
        for (int nt = 0; nt < 4; nt++)
#pragma unroll
            for (int rr = 0; rr < 4; rr++)
                Ys[wave][quad * 4 + rr][nt * 16 + l16] = acc[nt][rr];
        u32* yo = (u32*)y + ((size_t)(b * CT + rowbase + it * 16)) * (CD / 2) + h * 32;
#pragma unroll
        for (int p = 0; p < 8; p++) {
            const int idx = p * 64 + lane;
            const int row = idx >> 5, c2 = idx & 31;
            const float f0 = Ys[wave][row][2 * c2];
            const float f1 = Ys[wave][row][2 * c2 + 1];
            yo[(size_t)row * (CD / 2) + c2] = (u32)f2b(f0) | ((u32)f2b(f1) << 16);
        }
    }
}

// ---------------------------------------------------------------- emb pipeline
__global__ __launch_bounds__(256) void embsilu_kernel(const float* __restrict__ emb,
        float* __restrict__ se)
{
    const int i = blockIdx.x * 256 + threadIdx.x;
    if (i < CB * CTE) {
        const float e = emb[i];
        se[i] = e / (1.0f + __expf(-e));
    }
}
__global__ __launch_bounds__(256) void eoinit_kernel(const float* __restrict__ embB,
        float* __restrict__ eo)
{
    const int i = blockIdx.x * 256 + threadIdx.x;
    if (i < CB * CD2) eo[i] = embB[i & (CD2 - 1)];
}
__global__ __launch_bounds__(256) void embout2_kernel(const float* __restrict__ se,
        const float* __restrict__ embW, float* __restrict__ eo)
{
    const int jg = blockIdx.x & 15, kc = blockIdx.x >> 4;
    const int tid = threadIdx.x;
    const int jl = tid & 63, kgrp = tid >> 6;
    const int j = jg * 64 + jl;
    const int kbase = kc * 256 + kgrp * 64;
    const float* W = embW + (size_t)kbase * CD2 + j;
    const float* s0 = se + kbase;
    const float* s1 = s0 + CTE;
    const float* s2 = s1 + CTE;
    const float* s3 = s2 + CTE;
    float a0 = 0.0f, a1 = 0.0f, a2 = 0.0f, a3 = 0.0f;
#pragma unroll 8
    for (int kk = 0; kk < 64; kk++) {
        const float w = W[(size_t)kk * CD2];
        a0 = fmaf(s0[kk], w, a0);
        a1 = fmaf(s1[kk], w, a1);
        a2 = fmaf(s2[kk], w, a2);
        a3 = fmaf(s3[kk], w, a3);
    }
    __shared__ float red[4][4][64];   // [kgrp][b][j]
    red[kgrp][0][jl] = a0; red[kgrp][1][jl] = a1;
    red[kgrp][2][jl] = a2; red[kgrp][3][jl] = a3;
    __syncthreads();
    if (tid < 64) {
#pragma unroll
        for (int b = 0; b < 4; b++) {
            const float t = red[0][b][tid] + red[1][b][tid]
                          + red[2][b][tid] + red[3][b][tid];
            atomicAdd(&eo[(size_t)b * CD2 + jg * 64 + tid], t);
        }
    }
}

// ---------------------------------------------------------------- LN2 + stylization + silu: y bf16 -> s bf16
__global__ __launch_bounds__(256) void ln2_style_kernel(const u16* __restrict__ y,
        const float* __restrict__ g2, const float* __restrict__ bt2,
        const float* __restrict__ eo, u16* __restrict__ sout)
{
    const int row = blockIdx.x;
    const int tid = threadIdx.x;
    const int b = row >> 13;
    const u32 p = ((const u32*)(y + (size_t)row * CD))[tid];
    const float x0 = b2f((u16)(p & 0xffff));
    const float x1 = b2f((u16)(p >> 16));
    float s = x0 + x1;
    float sq = x0 * x0 + x1 * x1;
#pragma unroll
    for (int m = 1; m < 64; m <<= 1) { s += __shfl_xor(s, m); sq += __shfl_xor(sq, m); }
    __shared__ float red[8];
    const int wid = tid >> 6;
    if ((tid & 63) == 0) { red[wid] = s; red[wid + 4] = sq; }
    __syncthreads();
    s = red[0] + red[1] + red[2] + red[3];
    sq = red[4] + red[5] + red[6] + red[7];
    const float mu = s * (1.0f / CD);
    float var = sq * (1.0f / CD) - mu * mu;
    var = fmaxf(var, 0.0f);
    const float rs = rsqrtf(var + 1e-5f);
    const float2 gv = ((const float2*)g2)[tid];
    const float2 bv = ((const float2*)bt2)[tid];
    const float2 sc = ((const float2*)(eo + (size_t)b * CD2))[tid];
    const float2 sh = ((const float2*)(eo + (size_t)b * CD2 + CD))[tid];
    float h0 = (x0 - mu) * rs * gv.x + bv.x;
    float h1 = (x1 - mu) * rs * gv.y + bv.y;
    h0 = h0 * (1.0f + sc.x) + sh.x;
    h1 = h1 * (1.0f + sc.y) + sh.y;
    const float s0 = h0 / (1.0f + __expf(-h0));
    const float s1 = h1 / (1.0f + __expf(-h1));
    ((u32*)(sout + (size_t)row * CD))[tid] = (u32)f2b(s0) | ((u32)f2b(s1) << 16);
}

// ----------------------------------------------------------------
// Buffers:
//  d_out (64 MB fp32 out) as scratch until final GEMM:
//    R0 [0,32M):  k bf16 -> q bf16 (k dead after attn_kernel)
//    R1 [32M,64M): v bf16 -> y bf16
//  d_ws (~36.4 MB used):
//    ws+0        : xn bf16 (32 MB) -> s bf16
//    ws+33554432 : Wt bf16 x4 [n][k]: Wk,Wv,Wq,outW (2 MB)
//    ws+35651584 : pm/ps (512 KB, dead after ksm_norm) -> attn (512 KB fp32)
//    ws+36306944 : eo (16 KB fp32)
//    ws+36323328 : se (32 KB fp32, silu(emb))
extern "C" void kernel_launch(void* const* d_in, const int* in_sizes, int n_in,
                              void* d_out, int out_size, void* d_ws, size_t ws_size,
                              hipStream_t stream) {
    (void)in_sizes; (void)n_in; (void)out_size; (void)ws_size;
    const float* x    = (const float*)d_in[0];
    const float* emb  = (const float*)d_in[1];
    const float* mask = (const float*)d_in[2];
    const float* gamma= (const float*)d_in[3];
    const float* beta = (const float*)d_in[4];
    const float* Wq   = (const float*)d_in[5];
    const float* bq   = (const float*)d_in[6];
    const float* Wk   = (const float*)d_in[7];
    const float* bk   = (const float*)d_in[8];
    const float* Wv   = (const float*)d_in[9];
    const float* bv   = (const float*)d_in[10];
    const float* embW = (const float*)d_in[11];
    const float* embB = (const float*)d_in[12];
    const float* g2   = (const float*)d_in[13];
    const float* bt2  = (const float*)d_in[14];
    const float* outW = (const float*)d_in[15];
    const float* outb = (const float*)d_in[16];

    char* od = (char*)d_out;
    u16* kq  = (u16*)od;                        // R0: k then q
    u16* vy  = (u16*)(od + 33554432);           // R1: v then y
    float* outp = (float*)d_out;

    char* ws = (char*)d_ws;
    u16* xn   = (u16*)ws;                       // 32 MB, later s
    u16* WtK  = (u16*)(ws + 33554432);
    u16* WtV  = WtK + (size_t)CD * CD;
    u16* WtQ  = WtV + (size_t)CD * CD;
    u16* WtO  = WtQ + (size_t)CD * CD;
    float* pm   = (float*)(ws + 35651584);      // 256 KB
    float* ps   = (float*)(ws + 35651584 + 262144); // 256 KB
    float* attn = (float*)(ws + 35651584);      // reuses pm/ps region after ksm
    float* eo   = (float*)(ws + 36306944);
    float* se   = (float*)(ws + 36323328);

    wconv_kernel<<<dim3(64, 4), 256, 0, stream>>>(Wk, Wv, Wq, outW, WtK);
    ln1_kernel<<<CB * CT, 256, 0, stream>>>(x, gamma, beta, xn);
    embsilu_kernel<<<32, 256, 0, stream>>>(emb, se);
    eoinit_kernel<<<16, 256, 0, stream>>>(embB, eo);
    embout2_kernel<<<128, 256, 0, stream>>>(se, embW, eo);
    // fused k+v GEMM (mode 4): k -> kq, v -> vy
    gemm_mfma<<<2048, 256, 0, stream>>>(xn, WtK, bk, bv, kq, vy, mask, nullptr, 4);
    ksm_partial<<<128, 256, 0, stream>>>(kq, pm, ps);
    ksm_norm<<<128, 256, 0, stream>>>(kq, pm, ps);
    zero_kernel<<<512, 256, 0, stream>>>(attn, CB * CH * CDH * CDH);
    attn_kernel<<<512, 256, 0, stream>>>(kq, vy, attn);
    // k, v dead -> q into R0, y into R1
    gemm_mfma<<<1024, 256, 0, stream>>>(xn, WtQ, bq, nullptr, kq, nullptr, nullptr, nullptr, 0);
    y_mfma<<<1024, 256, 0, stream>>>(kq, attn, vy);
    ln2_style_kernel<<<CB * CT, 256, 0, stream>>>(vy, g2, bt2, eo, xn /* s */);
    gemm_mfma<<<1024, 256, 0, stream>>>(xn /* s */, WtO, outb, nullptr, outp, nullptr, nullptr, x, 3);
}

// Round 5
// 452.238 us; speedup vs baseline: 1.7361x; 1.0434x over previous
//
#include <hip/hip_runtime.h>
#include <cstdint>
#include <cstddef>

typedef unsigned short u16;
typedef unsigned int u32;
typedef __attribute__((ext_vector_type(8))) short short8;   // 8 x bf16 (4 VGPRs)
typedef __attribute__((ext_vector_type(4))) float f32x4;    // MFMA accumulator

static constexpr int CB = 4;
static constexpr int CT = 8192;
static constexpr int CD = 512;
static constexpr int CH = 8;
static constexpr int CDH = 64;
static constexpr int CTE = 2048;
static constexpr int CD2 = 1024;

__device__ __forceinline__ float b2f(u16 u) {
    return __uint_as_float(((u32)u) << 16);
}
__device__ __forceinline__ u16 f2b(float f) {
    u32 i = __float_as_uint(f);
    i = i + 0x7fffu + ((i >> 16) & 1u);   // round-to-nearest-even
    return (u16)(i >> 16);
}

typedef const __attribute__((address_space(1))) void* gas_p;
typedef __attribute__((address_space(3))) void* las_p;
#define GLD16(g, l) __builtin_amdgcn_global_load_lds((gas_p)(g), (las_p)(l), 16, 0, 0)

// ---------------------------------------------------------------- zero
__global__ __launch_bounds__(256) void zero_kernel(float* __restrict__ p, int n) {
    int i = blockIdx.x * 256 + threadIdx.x;
    if (i < n) p[i] = 0.0f;
}

// ---------------------------------------------------------------- W[k][n] fp32 -> Wt[n][k] bf16, tiled transpose
// grid = dim3(64, 4): 8x8 tiles of 64x64 per matrix; block 256
__global__ __launch_bounds__(256) void wconv_kernel(
        const float* __restrict__ W0, const float* __restrict__ W1,
        const float* __restrict__ W2, const float* __restrict__ W3,
        u16* __restrict__ Wt)
{
    const float* W;
    switch (blockIdx.y) {
        case 0: W = W0; break;
        case 1: W = W1; break;
        case 2: W = W2; break;
        default: W = W3; break;
    }
    u16* o = Wt + (size_t)blockIdx.y * CD * CD;
    const int k0 = (blockIdx.x >> 3) * 64;
    const int n0 = (blockIdx.x & 7) * 64;
    const int tid = threadIdx.x;
    __shared__ u16 tile[64][65];
    const int nn = tid & 63, kq = tid >> 6;
#pragma unroll
    for (int i = 0; i < 16; i++) {
        const int kk = i * 4 + kq;
        tile[kk][nn] = f2b(W[(size_t)(k0 + kk) * CD + n0 + nn]);  // coalesced read
    }
    __syncthreads();
    const int kk2 = tid & 63, nq = tid >> 6;
#pragma unroll
    for (int i = 0; i < 16; i++) {
        const int nn2 = i * 4 + nq;
        o[(size_t)(n0 + nn2) * CD + k0 + kk2] = tile[kk2][nn2];   // coalesced write
    }
}

// ---------------------------------------------------------------- LN1: fp32 x -> bf16 xn
__global__ __launch_bounds__(256) void ln1_kernel(const float* __restrict__ x,
        const float* __restrict__ g, const float* __restrict__ bt,
        u16* __restrict__ xn)
{
    const int row = blockIdx.x;
    const int tid = threadIdx.x;
    const float2 p = ((const float2*)(x + (size_t)row * CD))[tid];
    float s = p.x + p.y;
    float sq = p.x * p.x + p.y * p.y;
#pragma unroll
    for (int m = 1; m < 64; m <<= 1) { s += __shfl_xor(s, m); sq += __shfl_xor(sq, m); }
    __shared__ float red[8];
    const int wid = tid >> 6;
    if ((tid & 63) == 0) { red[wid] = s; red[wid + 4] = sq; }
    __syncthreads();
    s = red[0] + red[1] + red[2] + red[3];
    sq = red[4] + red[5] + red[6] + red[7];
    const float mu = s * (1.0f / CD);
    float var = sq * (1.0f / CD) - mu * mu;
    var = fmaxf(var, 0.0f);
    const float rs = rsqrtf(var + 1e-5f);
    const float2 gv = ((const float2*)g)[tid];
    const float2 bv = ((const float2*)bt)[tid];
    const float y0 = (p.x - mu) * rs * gv.x + bv.x;
    const float y1 = (p.y - mu) * rs * gv.y + bv.y;
    ((u32*)(xn + (size_t)row * CD))[tid] = (u32)f2b(y0) | ((u32)f2b(y1) << 16);
}

// ---------------------------------------------------------------- MFMA GEMM
// C[M,N] = A[M,K]bf16 @ Bt[N,K]bf16^T + bias, M=32768, K=512.
// mode 0 (q): N=512, out bf16 | mode 3 (o): N=512, + xres, out fp32
// mode 4 (kv fused): N=1024; cols<512 -> k (+(1-mask)*-1e6) into Cv,
//                    cols>=512 -> v (*mask) into Cv2. Bt = WtK||WtV contiguous.
// Tile 256x256, BK=32, 512 threads (8 waves of 128x64). 2 LDS buffers (64 KB),
// depth-1 prefetch with counted vmcnt(4) (T4), raw s_barrier, setprio (T5).
// 2x fewer staged bytes per FLOP vs 128x128 (DMA-throughput-bound regime).
// Bank-conflict-free via pre-swizzled global source + matching read swizzle.
// XCD-aware block swizzle (T1); grid uniform: 512 blk (mode 4) / 256 blk.
__global__ __launch_bounds__(512, 1) void gemm_mfma(
    const u16* __restrict__ A, const u16* __restrict__ Bt,
    const float* __restrict__ bias, const float* __restrict__ bias2,
    void* __restrict__ Cv, void* __restrict__ Cv2,
    const float* __restrict__ mask, const float* __restrict__ xres,
    int mode)
{
    __shared__ u16 SH[2][512][32];   // [buf][0..255 A rows | 256..511 B rows][32k] = 64 KB
    const int tid = threadIdx.x;
    const int wave = tid >> 6, lane = tid & 63;
    const int quad = lane >> 4, l16 = lane & 15;

    const int n = blockIdx.x;
    const int xcd = n & 7;
    int by, bx;
    if (mode == 4) { const int slot = n >> 3; by = xcd * 16 + (slot >> 2); bx = slot & 3; }
    else           { const int slot = n >> 3; by = xcd * 16 + (slot >> 1); bx = slot & 1; }
    const int row0 = by * 256;
    const int col0 = bx * 256;
    const int wm = (wave >> 2) * 128;      // 0 / 128
    const int wn = (wave & 3) * 64;        // 0..192

    // mode-4 per-block specialization (col0 is 256-aligned, so side is uniform)
    int emode = mode;
    const float* bptr = bias;
    void* cout = Cv;
    int ocol0 = col0;
    if (mode == 4) {
        if (col0 >= 512) { emode = 2; bptr = bias2; cout = Cv2; ocol0 = col0 - 512; }
        else emode = 1;
    }

    f32x4 acc[8][4];
#pragma unroll
    for (int mt = 0; mt < 8; mt++)
#pragma unroll
        for (int nt = 0; nt < 4; nt++)
            acc[mt][nt] = (f32x4){0.0f, 0.0f, 0.0f, 0.0f};

    // staging: wave w stages A rows [w*32, w*32+32) and B rows [w*32, w*32+32).
    // lane l -> row sub = l>>2, 16B slot = l&3 (linear LDS dest = base + l*16).
    // LDS[row][slot] holds global slot (slot ^ ((row>>1)&3)) -> source pre-swizzled.
    const int srow = lane >> 2;          // 0..15
    const int sslot = lane & 3;          // 16B slot
    const int swz = (srow >> 1) & 3;
    const int aw0 = wave * 32;
    const u16* gA0 = A + (size_t)(row0 + aw0 + srow) * CD + (sslot ^ swz) * 8;
    const u16* gA1 = gA0 + (size_t)16 * CD;
    const u16* gB0 = Bt + (size_t)(col0 + aw0 + srow) * CD + (sslot ^ swz) * 8;
    const u16* gB1 = gB0 + (size_t)16 * CD;

#define STAGE_T(bf, kt) do { \
        GLD16(gA0 + (kt) * 32, &SH[bf][aw0][0]); \
        GLD16(gA1 + (kt) * 32, &SH[bf][aw0 + 16][0]); \
        GLD16(gB0 + (kt) * 32, &SH[bf][256 + aw0][0]); \
        GLD16(gB1 + (kt) * 32, &SH[bf][256 + aw0 + 16][0]); \
    } while (0)

    STAGE_T(0, 0);

    const int swsel = (quad ^ ((l16 >> 1) & 3)) * 8;   // read-side swizzle

#pragma unroll
    for (int t = 0; t < 16; ++t) {
        const int bf = t & 1;
        if (t < 15) STAGE_T(bf ^ 1, t + 1);
        // wait own tile-t loads (counted, never 0 mid-loop) + join.
        // prev-iter's lgkmcnt(0)+barrier guarantees buffer bf's readers done.
        if (t < 15) asm volatile("s_waitcnt vmcnt(4)\ns_barrier" ::: "memory");
        else        asm volatile("s_waitcnt vmcnt(0)\ns_barrier" ::: "memory");

        short8 bfr[4];
#pragma unroll
        for (int nt = 0; nt < 4; nt++)
            bfr[nt] = *(const short8*)&SH[bf][256 + wn + nt * 16 + l16][swsel];
        __builtin_amdgcn_s_setprio(1);
#pragma unroll
        for (int mt = 0; mt < 8; mt++) {
            const short8 af = *(const short8*)&SH[bf][wm + mt * 16 + l16][swsel];
#pragma unroll
            for (int nt = 0; nt < 4; nt++)
                acc[mt][nt] = __builtin_amdgcn_mfma_f32_16x16x32_bf16(
                    af, bfr[nt], acc[mt][nt], 0, 0, 0);
        }
        __builtin_amdgcn_s_setprio(0);
        // all our LDS reads retired before anyone re-stages this buffer
        asm volatile("s_waitcnt lgkmcnt(0)\ns_barrier" ::: "memory");
    }
#undef STAGE_T

    if (emode == 3) {
        // direct fp32 stores (+xres): 4B/lane, 64B/quad-row, full sectors
#pragma unroll
        for (int mt = 0; mt < 8; mt++) {
            const int rbase = row0 + wm + mt * 16 + quad * 4;
#pragma unroll
            for (int r = 0; r < 4; r++) {
                const int row = rbase + r;
#pragma unroll
                for (int nt = 0; nt < 4; nt++) {
                    const int col = ocol0 + wn + nt * 16 + l16;
                    const float val = acc[mt][nt][r] + bptr[col];
                    ((float*)cout)[(size_t)row * CD + col] =
                        val + xres[(size_t)row * CD + col];
                }
            }
        }
    } else {
        // packed bf16 epilogue: stage 16x64 f32 strip in private padded LDS
        // region (reuse SH), then coalesced u32 row writes.
        float* stg = ((float*)&SH[0][0][0]) + wave * 1040;   // 16*65 floats/wave
#pragma unroll
        for (int mt = 0; mt < 8; mt++) {
#pragma unroll
            for (int r = 0; r < 4; r++) {
                const int rr = quad * 4 + r;
                const int grow = row0 + wm + mt * 16 + rr;
                float mval = 0.0f;
                if (emode == 1 || emode == 2) mval = mask[grow];
#pragma unroll
                for (int nt = 0; nt < 4; nt++) {
                    const int ocol = ocol0 + wn + nt * 16 + l16;
                    float val = acc[mt][nt][r] + bptr[ocol];
                    if (emode == 1) val += (1.0f - mval) * -1000000.0f;
                    else if (emode == 2) val *= mval;
                    stg[rr * 65 + nt * 16 + l16] = val;
                }
            }
            u16* cbase = (u16*)cout + (size_t)(row0 + wm + mt * 16) * CD + ocol0 + wn;
#pragma unroll
            for (int i = 0; i < 8; i++) {
                const int rr = i * 2 + (lane >> 5);
                const int c2 = lane & 31;
                const float f0 = stg[rr * 65 + 2 * c2];
                const float f1 = stg[rr * 65 + 2 * c2 + 1];
                ((u32*)(cbase + (size_t)rr * CD))[c2] =
                    (u32)f2b(f0) | ((u32)f2b(f1) << 16);
            }
        }
    }
}

// ---------------------------------------------------------------- k softmax over T (row-coalesced)
// pass 1: per-chunk max/sum partials. grid = B(4)*chunks(32) = 128; block 256.
__global__ __launch_bounds__(256) void ksm_partial(const u16* __restrict__ k,
        float* __restrict__ pm, float* __restrict__ ps)
{
    const int bid = blockIdx.x;
    const int b = bid >> 5, ch = bid & 31;
    const int tid = threadIdx.x;
    const u32* base = (const u32*)(k + (size_t)b * CT * CD + (size_t)ch * 256 * CD) + tid;
    float m0 = -3.0e38f, m1 = -3.0e38f;
#pragma unroll 8
    for (int r = 0; r < 256; ++r) {
        const u32 p = base[(size_t)r * 256];
        m0 = fmaxf(m0, b2f((u16)(p & 0xffff)));
        m1 = fmaxf(m1, b2f((u16)(p >> 16)));
    }
    float s0 = 0.0f, s1 = 0.0f;
#pragma unroll 8
    for (int r = 0; r < 256; ++r) {
        const u32 p = base[(size_t)r * 256];   // L2-resident re-read
        s0 += __expf(b2f((u16)(p & 0xffff)) - m0);
        s1 += __expf(b2f((u16)(p >> 16)) - m1);
    }
    const int d0 = tid * 2;
    pm[((size_t)b * CD + d0) * 32 + ch] = m0;
    pm[((size_t)b * CD + d0 + 1) * 32 + ch] = m1;
    ps[((size_t)b * CD + d0) * 32 + ch] = s0;
    ps[((size_t)b * CD + d0 + 1) * 32 + ch] = s1;
}

// pass 2: combine partials + normalize in place. grid = 128; block 256.
__global__ __launch_bounds__(256) void ksm_norm(u16* __restrict__ k,
        const float* __restrict__ pm, const float* __restrict__ ps)
{
    const int bid = blockIdx.x;
    const int b = bid >> 5, ch = bid & 31;
    const int tid = threadIdx.x;
    const int d0 = tid * 2;
    const float* pm0 = pm + ((size_t)b * CD + d0) * 32;
    const float* pm1 = pm0 + 32;
    const float* ps0 = ps + ((size_t)b * CD + d0) * 32;
    const float* ps1 = ps0 + 32;
    float M0 = -3.0e38f, M1 = -3.0e38f;
#pragma unroll
    for (int c = 0; c < 32; ++c) { M0 = fmaxf(M0, pm0[c]); M1 = fmaxf(M1, pm1[c]); }
    float S0 = 0.0f, S1 = 0.0f;
#pragma unroll
    for (int c = 0; c < 32; ++c) {
        S0 += ps0[c] * __expf(pm0[c] - M0);
        S1 += ps1[c] * __expf(pm1[c] - M1);
    }
    const float R0 = 1.0f / S0, R1 = 1.0f / S1;
    u32* base = (u32*)(k + (size_t)b * CT * CD + (size_t)ch * 256 * CD) + tid;
#pragma unroll 4
    for (int r = 0; r < 256; ++r) {
        const u32 p = base[(size_t)r * 256];
        const float x0 = __expf(b2f((u16)(p & 0xffff)) - M0) * R0;
        const float x1 = __expf(b2f((u16)(p >> 16)) - M1) * R1;
        base[(size_t)r * 256] = (u32)f2b(x0) | ((u32)f2b(x1) << 16);
    }
}

// ---------------------------------------------------------------- attn = sum_t k (outer) v, per (b,h)
// grid = 32 (b,h) * 16 tchunks = 512; block 256
__global__ __launch_bounds__(256) void attn_kernel(const u16* __restrict__ k,
        const u16* __restrict__ v, float* __restrict__ attn)
{
    const int bid = blockIdx.x;
    const int bh = bid >> 4, ch = bid & 15;
    const int b = bh >> 3, h = bh & 7;
    const int tid = threadIdx.x;
    __shared__ u16 Ks[32][64], Vs[32][64];
    const int ti = tid >> 4, tj = tid & 15;
    const int d0 = ti * 4, l0 = tj * 4;
    const int trow = tid >> 3, cg8 = (tid & 7) * 8;
    float acc[4][4];
#pragma unroll
    for (int r = 0; r < 4; r++)
#pragma unroll
        for (int c = 0; c < 4; c++) acc[r][c] = 0.0f;

    for (int st = 0; st < 16; st++) {
        const int t0 = ch * 512 + st * 32;
        const size_t goff = ((size_t)(b * CT + t0 + trow)) * CD + h * 64 + cg8;
        const uint4 kv4 = *(const uint4*)(k + goff);
        const uint4 vv4 = *(const uint4*)(v + goff);
        __syncthreads();
        *(uint4*)&Ks[trow][cg8] = kv4;
        *(uint4*)&Vs[trow][cg8] = vv4;
        __syncthreads();
#pragma unroll
        for (int tt = 0; tt < 32; tt++) {
            const ushort4 ka = *(const ushort4*)&Ks[tt][d0];
            const ushort4 va = *(const ushort4*)&Vs[tt][l0];
            const float kr[4] = { b2f(ka.x), b2f(ka.y), b2f(ka.z), b2f(ka.w) };
            const float vr[4] = { b2f(va.x), b2f(va.y), b2f(va.z), b2f(va.w) };
#pragma unroll
            for (int r = 0; r < 4; r++)
#pragma unroll
                for (int c = 0; c < 4; c++)
                    acc[r][c] = fmaf(kr[r], vr[c], acc[r][c]);
        }
    }
    float* ab = attn + (size_t)bh * 64 * 64;
#pragma unroll
    for (int r = 0; r < 4; r++)
#pragma unroll
        for (int c = 0; c < 4; c++)
            atomicAdd(&ab[(d0 + r) * 64 + l0 + c], acc[r][c]);
}

// ---------------------------------------------------------------- y = softmax(q over Dh) @ attn  (MFMA)
// grid = 32 (b,h) * 32 rowchunks = 1024; block 256 (4 waves), each wave 64 rows.
__global__ __launch_bounds__(256) void y_mfma(const u16* __restrict__ q,
        const float* __restrict__ attn, u16* __restrict__ y)
{
    const int bid = blockIdx.x;
    const int bh = bid >> 5;          // 0..31
    const int chunk = bid & 31;       // 0..31
    const int b = bh >> 3, h = bh & 7;
    const int tid = threadIdx.x;
    const int wave = tid >> 6, lane = tid & 63;
    const int quad = lane >> 4, l16 = lane & 15;

    __shared__ u16 Bh[64][72];        // Bt layout: [col l][k d], +8 pad keeps b128 align
    __shared__ u16 Bl[64][72];
    __shared__ float Ys[4][16][65];   // per-wave epilogue staging, padded

    const float* ab = attn + (size_t)bh * 64 * 64;
#pragma unroll
    for (int i = 0; i < 16; i++) {
        const int idx = i * 256 + tid;
        const int d = idx >> 6, l = idx & 63;
        const float a = ab[idx];
        const u16 hi = f2b(a);
        Bh[l][d] = hi;
        Bl[l][d] = f2b(a - b2f(hi));
    }
    __syncthreads();

    short8 bhf[4][2], blf[4][2];
#pragma unroll
    for (int nt = 0; nt < 4; nt++)
#pragma unroll
        for (int ks = 0; ks < 2; ks++) {
            bhf[nt][ks] = *(const short8*)&Bh[nt * 16 + l16][ks * 32 + quad * 8];
            blf[nt][ks] = *(const short8*)&Bl[nt * 16 + l16][ks * 32 + quad * 8];
        }

    const int rowbase = chunk * 256 + wave * 64;            // within this batch
    const size_t qb = ((size_t)(b * CT + rowbase)) * CD + h * 64;

#pragma unroll
    for (int it = 0; it < 4; it++) {
        const u16* qp = q + qb + (size_t)(it * 16 + l16) * CD + quad * 8;
        const uint4 q0 = *(const uint4*)qp;
        const uint4 q1 = *(const uint4*)(qp + 32);
        float xv[16];
        const u32 qw[8] = { q0.x, q0.y, q0.z, q0.w, q1.x, q1.y, q1.z, q1.w };
#pragma unroll
        for (int j = 0; j < 8; j++) {
            xv[2 * j]     = b2f((u16)(qw[j] & 0xffff));
            xv[2 * j + 1] = b2f((u16)(qw[j] >> 16));
        }
        float m = xv[0];
#pragma unroll
        for (int j = 1; j < 16; j++) m = fmaxf(m, xv[j]);
        m = fmaxf(m, __shfl_xor(m, 16));
        m = fmaxf(m, __shfl_xor(m, 32));
        float s = 0.0f;
#pragma unroll
        for (int j = 0; j < 16; j++) { xv[j] = __expf(xv[j] - m); s += xv[j]; }
        s += __shfl_xor(s, 16);
        s += __shfl_xor(s, 32);
        const float rinv = 1.0f / s;
        short8 ah[2], al[2];
#pragma unroll
        for (int ks = 0; ks < 2; ks++)
#pragma unroll
            for (int j = 0; j < 8; j++) {
                const float v = xv[ks * 8 + j] * rinv;
                const u16 hi = f2b(v);
                ah[ks][j] = (short)hi;
                al[ks][j] = (short)f2b(v - b2f(hi));
            }

        f32x4 acc[4];
#pragma unroll
        for (int nt = 0; nt < 4; nt++) acc[nt] = (f32x4){0.f, 0.f, 0.f, 0.f};
#pragma unroll
        for (int nt = 0; nt < 4; nt++) {
            acc[nt] = __builtin_amdgcn_mfma_f32_16x16x32_bf16(ah[0], bhf[nt][0], acc[nt], 0, 0, 0);
            acc[nt] = __builtin_amdgcn_mfma_f32_16x16x32_bf16(ah[1], bhf[nt][1], acc[nt], 0, 0, 0);
            acc[nt] = __builtin_amdgcn_mfma_f32_16x16x32_bf16(ah[0], blf[nt][0], acc[nt], 0, 0, 0);
            acc[nt] = __builtin_amdgcn_mfma_f32_16x16x32_bf16(ah[1], blf[nt][1], acc[nt], 0, 0, 0);
            acc[nt] = __builtin_amdgcn_mfma_f32_16x16x32_bf16(al[0], bhf[nt][0], acc[nt], 0, 0, 0);
            acc[nt] = __builtin_amdgcn_mfma_f32_16x16x32_bf16(al[1], bhf[nt][1], acc[nt], 0, 0, 0);
        }

#pragma unroll
        for (int nt = 0; nt < 4; nt++)
#pragma unroll
            for (int rr = 0; rr < 4; rr++)
                Ys[wave][quad * 4 + rr][nt * 16 + l16] = acc[nt][rr];
        u32* yo = (u32*)y + ((size_t)(b * CT + rowbase + it * 16)) * (CD / 2) + h * 32;
#pragma unroll
        for (int p = 0; p < 8; p++) {
            const int idx = p * 64 + lane;
            const int row = idx >> 5, c2 = idx & 31;
            const float f0 = Ys[wave][row][2 * c2];
            const float f1 = Ys[wave][row][2 * c2 + 1];
            yo[(size_t)row * (CD / 2) + c2] = (u32)f2b(f0) | ((u32)f2b(f1) << 16);
        }
    }
}

// ---------------------------------------------------------------- emb pipeline
__global__ __launch_bounds__(256) void embsilu_kernel(const float* __restrict__ emb,
        float* __restrict__ se)
{
    const int i = blockIdx.x * 256 + threadIdx.x;
    if (i < CB * CTE) {
        const float e = emb[i];
        se[i] = e / (1.0f + __expf(-e));
    }
}
__global__ __launch_bounds__(256) void eoinit_kernel(const float* __restrict__ embB,
        float* __restrict__ eo)
{
    const int i = blockIdx.x * 256 + threadIdx.x;
    if (i < CB * CD2) eo[i] = embB[i & (CD2 - 1)];
}
__global__ __launch_bounds__(256) void embout2_kernel(const float* __restrict__ se,
        const float* __restrict__ embW, float* __restrict__ eo)
{
    const int jg = blockIdx.x & 15, kc = blockIdx.x >> 4;
    const int tid = threadIdx.x;
    const int jl = tid & 63, kgrp = tid >> 6;
    const int j = jg * 64 + jl;
    const int kbase = kc * 256 + kgrp * 64;
    const float* W = embW + (size_t)kbase * CD2 + j;
    const float* s0 = se + kbase;
    const float* s1 = s0 + CTE;
    const float* s2 = s1 + CTE;
    const float* s3 = s2 + CTE;
    float a0 = 0.0f, a1 = 0.0f, a2 = 0.0f, a3 = 0.0f;
#pragma unroll 8
    for (int kk = 0; kk < 64; kk++) {
        const float w = W[(size_t)kk * CD2];
        a0 = fmaf(s0[kk], w, a0);
        a1 = fmaf(s1[kk], w, a1);
        a2 = fmaf(s2[kk], w, a2);
        a3 = fmaf(s3[kk], w, a3);
    }
    __shared__ float red[4][4][64];   // [kgrp][b][j]
    red[kgrp][0][jl] = a0; red[kgrp][1][jl] = a1;
    red[kgrp][2][jl] = a2; red[kgrp][3][jl] = a3;
    __syncthreads();
    if (tid < 64) {
#pragma unroll
        for (int b = 0; b < 4; b++) {
            const float t = red[0][b][tid] + red[1][b][tid]
                          + red[2][b][tid] + red[3][b][tid];
            atomicAdd(&eo[(size_t)b * CD2 + jg * 64 + tid], t);
        }
    }
}

// ---------------------------------------------------------------- LN2 + stylization + silu: y bf16 -> s bf16
__global__ __launch_bounds__(256) void ln2_style_kernel(const u16* __restrict__ y,
        const float* __restrict__ g2, const float* __restrict__ bt2,
        const float* __restrict__ eo, u16* __restrict__ sout)
{
    const int row = blockIdx.x;
    const int tid = threadIdx.x;
    const int b = row >> 13;
    const u32 p = ((const u32*)(y + (size_t)row * CD))[tid];
    const float x0 = b2f((u16)(p & 0xffff));
    const float x1 = b2f((u16)(p >> 16));
    float s = x0 + x1;
    float sq = x0 * x0 + x1 * x1;
#pragma unroll
    for (int m = 1; m < 64; m <<= 1) { s += __shfl_xor(s, m); sq += __shfl_xor(sq, m); }
    __shared__ float red[8];
    const int wid = tid >> 6;
    if ((tid & 63) == 0) { red[wid] = s; red[wid + 4] = sq; }
    __syncthreads();
    s = red[0] + red[1] + red[2] + red[3];
    sq = red[4] + red[5] + red[6] + red[7];
    const float mu = s * (1.0f / CD);
    float var = sq * (1.0f / CD) - mu * mu;
    var = fmaxf(var, 0.0f);
    const float rs = rsqrtf(var + 1e-5f);
    const float2 gv = ((const float2*)g2)[tid];
    const float2 bv = ((const float2*)bt2)[tid];
    const float2 sc = ((const float2*)(eo + (size_t)b * CD2))[tid];
    const float2 sh = ((const float2*)(eo + (size_t)b * CD2 + CD))[tid];
    float h0 = (x0 - mu) * rs * gv.x + bv.x;
    float h1 = (x1 - mu) * rs * gv.y + bv.y;
    h0 = h0 * (1.0f + sc.x) + sh.x;
    h1 = h1 * (1.0f + sc.y) + sh.y;
    const float s0 = h0 / (1.0f + __expf(-h0));
    const float s1 = h1 / (1.0f + __expf(-h1));
    ((u32*)(sout + (size_t)row * CD))[tid] = (u32)f2b(s0) | ((u32)f2b(s1) << 16);
}

// ----------------------------------------------------------------
// Buffers:
//  d_out (64 MB fp32 out) as scratch until final GEMM:
//    R0 [0,32M):  k bf16 -> q bf16 (k dead after attn_kernel)
//    R1 [32M,64M): v bf16 -> y bf16
//  d_ws (~36.4 MB used):
//    ws+0        : xn bf16 (32 MB) -> s bf16
//    ws+33554432 : Wt bf16 x4 [n][k]: Wk,Wv,Wq,outW (2 MB)
//    ws+35651584 : pm/ps (512 KB, dead after ksm_norm) -> attn (512 KB fp32)
//    ws+36306944 : eo (16 KB fp32)
//    ws+36323328 : se (32 KB fp32, silu(emb))
extern "C" void kernel_launch(void* const* d_in, const int* in_sizes, int n_in,
                              void* d_out, int out_size, void* d_ws, size_t ws_size,
                              hipStream_t stream) {
    (void)in_sizes; (void)n_in; (void)out_size; (void)ws_size;
    const float* x    = (const float*)d_in[0];
    const float* emb  = (const float*)d_in[1];
    const float* mask = (const float*)d_in[2];
    const float* gamma= (const float*)d_in[3];
    const float* beta = (const float*)d_in[4];
    const float* Wq   = (const float*)d_in[5];
    const float* bq   = (const float*)d_in[6];
    const float* Wk   = (const float*)d_in[7];
    const float* bk   = (const float*)d_in[8];
    const float* Wv   = (const float*)d_in[9];
    const float* bv   = (const float*)d_in[10];
    const float* embW = (const float*)d_in[11];
    const float* embB = (const float*)d_in[12];
    const float* g2   = (const float*)d_in[13];
    const float* bt2  = (const float*)d_in[14];
    const float* outW = (const float*)d_in[15];
    const float* outb = (const float*)d_in[16];

    char* od = (char*)d_out;
    u16* kq  = (u16*)od;                        // R0: k then q
    u16* vy  = (u16*)(od + 33554432);           // R1: v then y
    float* outp = (float*)d_out;

    char* ws = (char*)d_ws;
    u16* xn   = (u16*)ws;                       // 32 MB, later s
    u16* WtK  = (u16*)(ws + 33554432);
    u16* WtV  = WtK + (size_t)CD * CD;
    u16* WtQ  = WtV + (size_t)CD * CD;
    u16* WtO  = WtQ + (size_t)CD * CD;
    float* pm   = (float*)(ws + 35651584);      // 256 KB
    float* ps   = (float*)(ws + 35651584 + 262144); // 256 KB
    float* attn = (float*)(ws + 35651584);      // reuses pm/ps region after ksm
    float* eo   = (float*)(ws + 36306944);
    float* se   = (float*)(ws + 36323328);

    wconv_kernel<<<dim3(64, 4), 256, 0, stream>>>(Wk, Wv, Wq, outW, WtK);
    ln1_kernel<<<CB * CT, 256, 0, stream>>>(x, gamma, beta, xn);
    embsilu_kernel<<<32, 256, 0, stream>>>(emb, se);
    eoinit_kernel<<<16, 256, 0, stream>>>(embB, eo);
    embout2_kernel<<<128, 256, 0, stream>>>(se, embW, eo);
    // fused k+v GEMM (mode 4): k -> kq, v -> vy
    gemm_mfma<<<512, 512, 0, stream>>>(xn, WtK, bk, bv, kq, vy, mask, nullptr, 4);
    ksm_partial<<<128, 256, 0, stream>>>(kq, pm, ps);
    ksm_norm<<<128, 256, 0, stream>>>(kq, pm, ps);
    zero_kernel<<<512, 256, 0, stream>>>(attn, CB * CH * CDH * CDH);
    attn_kernel<<<512, 256, 0, stream>>>(kq, vy, attn);
    // k, v dead -> q into R0, y into R1
    gemm_mfma<<<256, 512, 0, stream>>>(xn, WtQ, bq, nullptr, kq, nullptr, nullptr, nullptr, 0);
    y_mfma<<<1024, 256, 0, stream>>>(kq, attn, vy);
    ln2_style_kernel<<<CB * CT, 256, 0, stream>>>(vy, g2, bt2, eo, xn /* s */);
    gemm_mfma<<<256, 512, 0, stream>>>(xn /* s */, WtO, outb, nullptr, outp, nullptr, nullptr, x, 3);
}

// Round 7
// 412.501 us; speedup vs baseline: 1.9033x; 1.0963x over previous
//
#include <hip/hip_runtime.h>
#include <cstdint>
#include <cstddef>

typedef unsigned short u16;
typedef unsigned int u32;
typedef __attribute__((ext_vector_type(8))) short short8;   // 8 x bf16 (4 VGPRs)
typedef __attribute__((ext_vector_type(4))) short short4v;  // 4 x bf16 (2 VGPRs)
typedef __attribute__((ext_vector_type(4))) float f32x4;    // MFMA accumulator

static constexpr int CB = 4;
static constexpr int CT = 8192;
static constexpr int CD = 512;
static constexpr int CH = 8;
static constexpr int CDH = 64;
static constexpr int CTE = 2048;
static constexpr int CD2 = 1024;

__device__ __forceinline__ float b2f(u16 u) {
    return __uint_as_float(((u32)u) << 16);
}
__device__ __forceinline__ u16 f2b(float f) {
    u32 i = __float_as_uint(f);
    i = i + 0x7fffu + ((i >> 16) & 1u);   // round-to-nearest-even
    return (u16)(i >> 16);
}

typedef const __attribute__((address_space(1))) void* gas_p;
typedef __attribute__((address_space(3))) void* las_p;
#define GLD16(g, l) __builtin_amdgcn_global_load_lds((gas_p)(g), (las_p)(l), 16, 0, 0)

// ---------------------------------------------------------------- zero
__global__ __launch_bounds__(256) void zero_kernel(float* __restrict__ p, int n) {
    int i = blockIdx.x * 256 + threadIdx.x;
    if (i < n) p[i] = 0.0f;
}

// ---------------------------------------------------------------- W[k][n] fp32 -> Wt[n][k] bf16, tiled transpose
// grid = dim3(64, 4): 8x8 tiles of 64x64 per matrix; block 256
__global__ __launch_bounds__(256) void wconv_kernel(
        const float* __restrict__ W0, const float* __restrict__ W1,
        const float* __restrict__ W2, const float* __restrict__ W3,
        u16* __restrict__ Wt)
{
    const float* W;
    switch (blockIdx.y) {
        case 0: W = W0; break;
        case 1: W = W1; break;
        case 2: W = W2; break;
        default: W = W3; break;
    }
    u16* o = Wt + (size_t)blockIdx.y * CD * CD;
    const int k0 = (blockIdx.x >> 3) * 64;
    const int n0 = (blockIdx.x & 7) * 64;
    const int tid = threadIdx.x;
    __shared__ u16 tile[64][65];
    const int nn = tid & 63, kq = tid >> 6;
#pragma unroll
    for (int i = 0; i < 16; i++) {
        const int kk = i * 4 + kq;
        tile[kk][nn] = f2b(W[(size_t)(k0 + kk) * CD + n0 + nn]);  // coalesced read
    }
    __syncthreads();
    const int kk2 = tid & 63, nq = tid >> 6;
#pragma unroll
    for (int i = 0; i < 16; i++) {
        const int nn2 = i * 4 + nq;
        o[(size_t)(n0 + nn2) * CD + k0 + kk2] = tile[kk2][nn2];   // coalesced write
    }
}

// ---------------------------------------------------------------- LN1: fp32 x -> bf16 xn
__global__ __launch_bounds__(256) void ln1_kernel(const float* __restrict__ x,
        const float* __restrict__ g, const float* __restrict__ bt,
        u16* __restrict__ xn)
{
    const int row = blockIdx.x;
    const int tid = threadIdx.x;
    const float2 p = ((const float2*)(x + (size_t)row * CD))[tid];
    float s = p.x + p.y;
    float sq = p.x * p.x + p.y * p.y;
#pragma unroll
    for (int m = 1; m < 64; m <<= 1) { s += __shfl_xor(s, m); sq += __shfl_xor(sq, m); }
    __shared__ float red[8];
    const int wid = tid >> 6;
    if ((tid & 63) == 0) { red[wid] = s; red[wid + 4] = sq; }
    __syncthreads();
    s = red[0] + red[1] + red[2] + red[3];
    sq = red[4] + red[5] + red[6] + red[7];
    const float mu = s * (1.0f / CD);
    float var = sq * (1.0f / CD) - mu * mu;
    var = fmaxf(var, 0.0f);
    const float rs = rsqrtf(var + 1e-5f);
    const float2 gv = ((const float2*)g)[tid];
    const float2 bv = ((const float2*)bt)[tid];
    const float y0 = (p.x - mu) * rs * gv.x + bv.x;
    const float y1 = (p.y - mu) * rs * gv.y + bv.y;
    ((u32*)(xn + (size_t)row * CD))[tid] = (u32)f2b(y0) | ((u32)f2b(y1) << 16);
}

// ---------------------------------------------------------------- MFMA GEMM
// C[M,N] = A[M,K]bf16 @ Bt[N,K]bf16^T + bias, M=32768, K=512.
// mode 0 (q): N=512, out bf16 | mode 3 (o): N=512, + xres, out fp32
// mode 4 (kv fused): N=1024; cols<512 -> k (+(1-mask)*-1e6) into Cv,
//                    cols>=512 -> v (*mask) into Cv2. Bt = WtK||WtV contiguous.
// Tile 256x256, BK=32, 512 threads (8 waves of 128x64). 2 LDS buffers (64 KB),
// depth-1 prefetch with counted vmcnt(4) (T4), raw s_barrier, setprio (T5).
// Bank-conflict-free via pre-swizzled global source + matching read swizzle.
// XCD-aware block swizzle (T1); grid uniform: 512 blk (mode 4) / 256 blk.
__global__ __launch_bounds__(512, 1) void gemm_mfma(
    const u16* __restrict__ A, const u16* __restrict__ Bt,
    const float* __restrict__ bias, const float* __restrict__ bias2,
    void* __restrict__ Cv, void* __restrict__ Cv2,
    const float* __restrict__ mask, const float* __restrict__ xres,
    int mode)
{
    __shared__ u16 SH[2][512][32];   // [buf][0..255 A rows | 256..511 B rows][32k] = 64 KB
    const int tid = threadIdx.x;
    const int wave = tid >> 6, lane = tid & 63;
    const int quad = lane >> 4, l16 = lane & 15;

    const int n = blockIdx.x;
    const int xcd = n & 7;
    int by, bx;
    if (mode == 4) { const int slot = n >> 3; by = xcd * 16 + (slot >> 2); bx = slot & 3; }
    else           { const int slot = n >> 3; by = xcd * 16 + (slot >> 1); bx = slot & 1; }
    const int row0 = by * 256;
    const int col0 = bx * 256;
    const int wm = (wave >> 2) * 128;      // 0 / 128
    const int wn = (wave & 3) * 64;        // 0..192

    // mode-4 per-block specialization (col0 is 256-aligned, so side is uniform)
    int emode = mode;
    const float* bptr = bias;
    void* cout = Cv;
    int ocol0 = col0;
    if (mode == 4) {
        if (col0 >= 512) { emode = 2; bptr = bias2; cout = Cv2; ocol0 = col0 - 512; }
        else emode = 1;
    }

    f32x4 acc[8][4];
#pragma unroll
    for (int mt = 0; mt < 8; mt++)
#pragma unroll
        for (int nt = 0; nt < 4; nt++)
            acc[mt][nt] = (f32x4){0.0f, 0.0f, 0.0f, 0.0f};

    // staging: wave w stages A rows [w*32, w*32+32) and B rows [w*32, w*32+32).
    const int srow = lane >> 2;          // 0..15
    const int sslot = lane & 3;          // 16B slot
    const int swz = (srow >> 1) & 3;
    const int aw0 = wave * 32;
    const u16* gA0 = A + (size_t)(row0 + aw0 + srow) * CD + (sslot ^ swz) * 8;
    const u16* gA1 = gA0 + (size_t)16 * CD;
    const u16* gB0 = Bt + (size_t)(col0 + aw0 + srow) * CD + (sslot ^ swz) * 8;
    const u16* gB1 = gB0 + (size_t)16 * CD;

#define STAGE_T(bf, kt) do { \
        GLD16(gA0 + (kt) * 32, &SH[bf][aw0][0]); \
        GLD16(gA1 + (kt) * 32, &SH[bf][aw0 + 16][0]); \
        GLD16(gB0 + (kt) * 32, &SH[bf][256 + aw0][0]); \
        GLD16(gB1 + (kt) * 32, &SH[bf][256 + aw0 + 16][0]); \
    } while (0)

    STAGE_T(0, 0);

    const int swsel = (quad ^ ((l16 >> 1) & 3)) * 8;   // read-side swizzle

#pragma unroll
    for (int t = 0; t < 16; ++t) {
        const int bf = t & 1;
        if (t < 15) STAGE_T(bf ^ 1, t + 1);
        if (t < 15) asm volatile("s_waitcnt vmcnt(4)\ns_barrier" ::: "memory");
        else        asm volatile("s_waitcnt vmcnt(0)\ns_barrier" ::: "memory");

        short8 bfr[4];
#pragma unroll
        for (int nt = 0; nt < 4; nt++)
            bfr[nt] = *(const short8*)&SH[bf][256 + wn + nt * 16 + l16][swsel];
        __builtin_amdgcn_s_setprio(1);
#pragma unroll
        for (int mt = 0; mt < 8; mt++) {
            const short8 af = *(const short8*)&SH[bf][wm + mt * 16 + l16][swsel];
#pragma unroll
            for (int nt = 0; nt < 4; nt++)
                acc[mt][nt] = __builtin_amdgcn_mfma_f32_16x16x32_bf16(
                    af, bfr[nt], acc[mt][nt], 0, 0, 0);
        }
        __builtin_amdgcn_s_setprio(0);
        asm volatile("s_waitcnt lgkmcnt(0)\ns_barrier" ::: "memory");
    }
#undef STAGE_T

    if (emode == 3) {
#pragma unroll
        for (int mt = 0; mt < 8; mt++) {
            const int rbase = row0 + wm + mt * 16 + quad * 4;
#pragma unroll
            for (int r = 0; r < 4; r++) {
                const int row = rbase + r;
#pragma unroll
                for (int nt = 0; nt < 4; nt++) {
                    const int col = ocol0 + wn + nt * 16 + l16;
                    const float val = acc[mt][nt][r] + bptr[col];
                    ((float*)cout)[(size_t)row * CD + col] =
                        val + xres[(size_t)row * CD + col];
                }
            }
        }
    } else {
        // packed bf16 epilogue via padded LDS strip, coalesced u32 row writes
        float* stg = ((float*)&SH[0][0][0]) + wave * 1040;   // 16*65 floats/wave
#pragma unroll
        for (int mt = 0; mt < 8; mt++) {
#pragma unroll
            for (int r = 0; r < 4; r++) {
                const int rr = quad * 4 + r;
                const int grow = row0 + wm + mt * 16 + rr;
                float mval = 0.0f;
                if (emode == 1 || emode == 2) mval = mask[grow];
#pragma unroll
                for (int nt = 0; nt < 4; nt++) {
                    const int ocol = ocol0 + wn + nt * 16 + l16;
                    float val = acc[mt][nt][r] + bptr[ocol];
                    if (emode == 1) val += (1.0f - mval) * -1000000.0f;
                    else if (emode == 2) val *= mval;
                    stg[rr * 65 + nt * 16 + l16] = val;
                }
            }
            u16* cbase = (u16*)cout + (size_t)(row0 + wm + mt * 16) * CD + ocol0 + wn;
#pragma unroll
            for (int i = 0; i < 8; i++) {
                const int rr = i * 2 + (lane >> 5);
                const int c2 = lane & 31;
                const float f0 = stg[rr * 65 + 2 * c2];
                const float f1 = stg[rr * 65 + 2 * c2 + 1];
                ((u32*)(cbase + (size_t)rr * CD))[c2] =
                    (u32)f2b(f0) | ((u32)f2b(f1) << 16);
            }
        }
    }
}

// ---------------------------------------------------------------- k softmax over T (row-coalesced)
// pass 1: per-chunk max/sum partials. grid = B(4)*chunks(32) = 128; block 256.
__global__ __launch_bounds__(256) void ksm_partial(const u16* __restrict__ k,
        float* __restrict__ pm, float* __restrict__ ps)
{
    const int bid = blockIdx.x;
    const int b = bid >> 5, ch = bid & 31;
    const int tid = threadIdx.x;
    const u32* base = (const u32*)(k + (size_t)b * CT * CD + (size_t)ch * 256 * CD) + tid;
    float m0 = -3.0e38f, m1 = -3.0e38f;
#pragma unroll 8
    for (int r = 0; r < 256; ++r) {
        const u32 p = base[(size_t)r * 256];
        m0 = fmaxf(m0, b2f((u16)(p & 0xffff)));
        m1 = fmaxf(m1, b2f((u16)(p >> 16)));
    }
    float s0 = 0.0f, s1 = 0.0f;
#pragma unroll 8
    for (int r = 0; r < 256; ++r) {
        const u32 p = base[(size_t)r * 256];   // L2-resident re-read
        s0 += __expf(b2f((u16)(p & 0xffff)) - m0);
        s1 += __expf(b2f((u16)(p >> 16)) - m1);
    }
    const int d0 = tid * 2;
    pm[((size_t)b * CD + d0) * 32 + ch] = m0;
    pm[((size_t)b * CD + d0 + 1) * 32 + ch] = m1;
    ps[((size_t)b * CD + d0) * 32 + ch] = s0;
    ps[((size_t)b * CD + d0 + 1) * 32 + ch] = s1;
}

// pass 2: combine partials + normalize in place. grid = 128; block 256.
__global__ __launch_bounds__(256) void ksm_norm(u16* __restrict__ k,
        const float* __restrict__ pm, const float* __restrict__ ps)
{
    const int bid = blockIdx.x;
    const int b = bid >> 5, ch = bid & 31;
    const int tid = threadIdx.x;
    const int d0 = tid * 2;
    const float* pm0 = pm + ((size_t)b * CD + d0) * 32;
    const float* pm1 = pm0 + 32;
    const float* ps0 = ps + ((size_t)b * CD + d0) * 32;
    const float* ps1 = ps0 + 32;
    float M0 = -3.0e38f, M1 = -3.0e38f;
#pragma unroll
    for (int c = 0; c < 32; ++c) { M0 = fmaxf(M0, pm0[c]); M1 = fmaxf(M1, pm1[c]); }
    float S0 = 0.0f, S1 = 0.0f;
#pragma unroll
    for (int c = 0; c < 32; ++c) {
        S0 += ps0[c] * __expf(pm0[c] - M0);
        S1 += ps1[c] * __expf(pm1[c] - M1);
    }
    const float R0 = 1.0f / S0, R1 = 1.0f / S1;
    u32* base = (u32*)(k + (size_t)b * CT * CD + (size_t)ch * 256 * CD) + tid;
#pragma unroll 4
    for (int r = 0; r < 256; ++r) {
        const u32 p = base[(size_t)r * 256];
        const float x0 = __expf(b2f((u16)(p & 0xffff)) - M0) * R0;
        const float x1 = __expf(b2f((u16)(p >> 16)) - M1) * R1;
        base[(size_t)r * 256] = (u32)f2b(x0) | ((u32)f2b(x1) << 16);
    }
}

// ---------------------------------------------------------------- attn = k^T @ v per (b,h)  (MFMA + tr_read)
// grid = 32 (b,h) * 16 tchunks = 512; block 256 = 4 INDEPENDENT waves.
// Each wave owns 128 t (4 K-steps of 32), private 2x8KB LDS double buffer,
// no barriers in loop: per-wave counted vmcnt + lgkmcnt only.
// LDS tile per (buf,kv): [4 dblk][32 t][16 d] u16 subtiles; GLD16 dest is
// linear (base + lane*16).
// tr_read slice semantics (m156 reconciled): each lane reads its OWN 8B slice;
// the 16-lane group's 128B region (4 t-rows x 16 d) is transposed so lane l16
// receives column d=l16, rows j=0..3. Lane addr = base + quad*256 + l16*8;
// offset:128 -> next 4 t. So two reads give k[t=quad*8+j][d=l16], j=0..7.
__global__ __launch_bounds__(256) void attn_mfma(const u16* __restrict__ k,
        const u16* __restrict__ v, float* __restrict__ attn)
{
    const int bid = blockIdx.x;
    const int bh = bid >> 4, ch = bid & 15;
    const int b = bh >> 3, h = bh & 7;
    const int tid = threadIdx.x;
    const int wave = tid >> 6, lane = tid & 63;
    const int quad = lane >> 4, l16 = lane & 15;

    __shared__ u16 SH[4][2][2][2048];   // [wave][buf][k/v][dblk*512 + t*16 + d] = 64 KB

    f32x4 acc[4][4];
#pragma unroll
    for (int mt = 0; mt < 4; mt++)
#pragma unroll
        for (int nt = 0; nt < 4; nt++)
            acc[mt][nt] = (f32x4){0.0f, 0.0f, 0.0f, 0.0f};

    // staging source: lane l -> t = l>>1, d8 = (l&1)*8 (LDS dest = base + l*16B)
    const size_t rb = (size_t)(b * CT + ch * 512 + wave * 128 + (lane >> 1)) * CD
                    + h * 64 + (lane & 1) * 8;
    const u16* gk = k + rb;
    const u16* gv = v + rb;

#define ASTAGE(bf, i) do { \
        const size_t o_ = (size_t)(i) * 32 * CD; \
        GLD16(gk + o_,      &SH[wave][bf][0][0]); \
        GLD16(gk + o_ + 16, &SH[wave][bf][0][512]); \
        GLD16(gk + o_ + 32, &SH[wave][bf][0][1024]); \
        GLD16(gk + o_ + 48, &SH[wave][bf][0][1536]); \
        GLD16(gv + o_,      &SH[wave][bf][1][0]); \
        GLD16(gv + o_ + 16, &SH[wave][bf][1][512]); \
        GLD16(gv + o_ + 32, &SH[wave][bf][1][1024]); \
        GLD16(gv + o_ + 48, &SH[wave][bf][1][1536]); \
    } while (0)

    ASTAGE(0, 0);

    const u32 lbase = (u32)(uintptr_t)(las_p)&SH[wave][0][0][0];
    const u32 atr = lbase + quad * 256 + l16 * 8;   // lane's 8B slice of its group's 128B region

    for (int i = 0; i < 4; ++i) {
        const int bf = i & 1;
        if (i < 3) {
            ASTAGE(bf ^ 1, i + 1);
            asm volatile("s_waitcnt vmcnt(8)" ::: "memory");   // cur-buf loads done
        } else {
            asm volatile("s_waitcnt vmcnt(0)" ::: "memory");
        }
        const u32 ak = atr + bf * 8192;
        const u32 av = ak + 4096;
        short4v kh0[4], kh1[4], vh0[4], vh1[4];
#pragma unroll
        for (int db = 0; db < 4; db++) {
            asm volatile("ds_read_b64_tr_b16 %0, %2 offset:0\n\t"
                         "ds_read_b64_tr_b16 %1, %2 offset:128"
                         : "=&v"(kh0[db]), "=&v"(kh1[db])
                         : "v"(ak + db * 1024));
            asm volatile("ds_read_b64_tr_b16 %0, %2 offset:0\n\t"
                         "ds_read_b64_tr_b16 %1, %2 offset:128"
                         : "=&v"(vh0[db]), "=&v"(vh1[db])
                         : "v"(av + db * 1024));
        }
        asm volatile("s_waitcnt lgkmcnt(0)" ::: "memory");
        __builtin_amdgcn_sched_barrier(0);                     // rule #18
        short8 kf[4], vf[4];
#pragma unroll
        for (int db = 0; db < 4; db++) {
            kf[db] = __builtin_shufflevector(kh0[db], kh1[db], 0, 1, 2, 3, 4, 5, 6, 7);
            vf[db] = __builtin_shufflevector(vh0[db], vh1[db], 0, 1, 2, 3, 4, 5, 6, 7);
        }
#pragma unroll
        for (int mt = 0; mt < 4; mt++)
#pragma unroll
            for (int nt = 0; nt < 4; nt++)
                acc[mt][nt] = __builtin_amdgcn_mfma_f32_16x16x32_bf16(
                    kf[mt], vf[nt], acc[mt][nt], 0, 0, 0);
    }
#undef ASTAGE

    // cross-wave reduce through LDS (reuse staging space; per-wave region private)
    float* Cw = (float*)&SH[wave][0][0][0];
#pragma unroll
    for (int mt = 0; mt < 4; mt++)
#pragma unroll
        for (int nt = 0; nt < 4; nt++)
#pragma unroll
            for (int r = 0; r < 4; r++)
                Cw[(mt * 16 + quad * 4 + r) * 64 + nt * 16 + l16] = acc[mt][nt][r];
    __syncthreads();
    const float* C0 = (const float*)&SH[0][0][0][0];
    float* ab = attn + (size_t)bh * 4096;
#pragma unroll
    for (int i = 0; i < 16; i++) {
        const int idx = i * 256 + tid;
        atomicAdd(&ab[idx],
                  C0[idx] + C0[idx + 4096] + C0[idx + 8192] + C0[idx + 12288]);
    }
}

// ---------------------------------------------------------------- y = softmax(q over Dh) @ attn  (MFMA)
// grid = 32 (b,h) * 32 rowchunks = 1024; block 256 (4 waves), each wave 64 rows.
__global__ __launch_bounds__(256) void y_mfma(const u16* __restrict__ q,
        const float* __restrict__ attn, u16* __restrict__ y)
{
    const int bid = blockIdx.x;
    const int bh = bid >> 5;          // 0..31
    const int chunk = bid & 31;       // 0..31
    const int b = bh >> 3, h = bh & 7;
    const int tid = threadIdx.x;
    const int wave = tid >> 6, lane = tid & 63;
    const int quad = lane >> 4, l16 = lane & 15;

    __shared__ u16 Bh[64][72];        // Bt layout: [col l][k d], +8 pad keeps b128 align
    __shared__ u16 Bl[64][72];
    __shared__ float Ys[4][16][65];   // per-wave epilogue staging, padded

    const float* ab = attn + (size_t)bh * 64 * 64;
#pragma unroll
    for (int i = 0; i < 16; i++) {
        const int idx = i * 256 + tid;
        const int d = idx >> 6, l = idx & 63;
        const float a = ab[idx];
        const u16 hi = f2b(a);
        Bh[l][d] = hi;
        Bl[l][d] = f2b(a - b2f(hi));
    }
    __syncthreads();

    short8 bhf[4][2], blf[4][2];
#pragma unroll
    for (int nt = 0; nt < 4; nt++)
#pragma unroll
        for (int ks = 0; ks < 2; ks++) {
            bhf[nt][ks] = *(const short8*)&Bh[nt * 16 + l16][ks * 32 + quad * 8];
            blf[nt][ks] = *(const short8*)&Bl[nt * 16 + l16][ks * 32 + quad * 8];
        }

    const int rowbase = chunk * 256 + wave * 64;            // within this batch
    const size_t qb = ((size_t)(b * CT + rowbase)) * CD + h * 64;

#pragma unroll
    for (int it = 0; it < 4; it++) {
        const u16* qp = q + qb + (size_t)(it * 16 + l16) * CD + quad * 8;
        const uint4 q0 = *(const uint4*)qp;
        const uint4 q1 = *(const uint4*)(qp + 32);
        float xv[16];
        const u32 qw[8] = { q0.x, q0.y, q0.z, q0.w, q1.x, q1.y, q1.z, q1.w };
#pragma unroll
        for (int j = 0; j < 8; j++) {
            xv[2 * j]     = b2f((u16)(qw[j] & 0xffff));
            xv[2 * j + 1] = b2f((u16)(qw[j] >> 16));
        }
        float m = xv[0];
#pragma unroll
        for (int j = 1; j < 16; j++) m = fmaxf(m, xv[j]);
        m = fmaxf(m, __shfl_xor(m, 16));
        m = fmaxf(m, __shfl_xor(m, 32));
        float s = 0.0f;
#pragma unroll
        for (int j = 0; j < 16; j++) { xv[j] = __expf(xv[j] - m); s += xv[j]; }
        s += __shfl_xor(s, 16);
        s += __shfl_xor(s, 32);
        const float rinv = 1.0f / s;
        short8 ah[2], al[2];
#pragma unroll
        for (int ks = 0; ks < 2; ks++)
#pragma unroll
            for (int j = 0; j < 8; j++) {
                const float v = xv[ks * 8 + j] * rinv;
                const u16 hi = f2b(v);
                ah[ks][j] = (short)hi;
                al[ks][j] = (short)f2b(v - b2f(hi));
            }

        f32x4 acc[4];
#pragma unroll
        for (int nt = 0; nt < 4; nt++) acc[nt] = (f32x4){0.f, 0.f, 0.f, 0.f};
#pragma unroll
        for (int nt = 0; nt < 4; nt++) {
            acc[nt] = __builtin_amdgcn_mfma_f32_16x16x32_bf16(ah[0], bhf[nt][0], acc[nt], 0, 0, 0);
            acc[nt] = __builtin_amdgcn_mfma_f32_16x16x32_bf16(ah[1], bhf[nt][1], acc[nt], 0, 0, 0);
            acc[nt] = __builtin_amdgcn_mfma_f32_16x16x32_bf16(ah[0], blf[nt][0], acc[nt], 0, 0, 0);
            acc[nt] = __builtin_amdgcn_mfma_f32_16x16x32_bf16(ah[1], blf[nt][1], acc[nt], 0, 0, 0);
            acc[nt] = __builtin_amdgcn_mfma_f32_16x16x32_bf16(al[0], bhf[nt][0], acc[nt], 0, 0, 0);
            acc[nt] = __builtin_amdgcn_mfma_f32_16x16x32_bf16(al[1], bhf[nt][1], acc[nt], 0, 0, 0);
        }

#pragma unroll
        for (int nt = 0; nt < 4; nt++)
#pragma unroll
            for (int rr = 0; rr < 4; rr++)
                Ys[wave][quad * 4 + rr][nt * 16 + l16] = acc[nt][rr];
        u32* yo = (u32*)y + ((size_t)(b * CT + rowbase + it * 16)) * (CD / 2) + h * 32;
#pragma unroll
        for (int p = 0; p < 8; p++) {
            const int idx = p * 64 + lane;
            const int row = idx >> 5, c2 = idx & 31;
            const float f0 = Ys[wave][row][2 * c2];
            const float f1 = Ys[wave][row][2 * c2 + 1];
            yo[(size_t)row * (CD / 2) + c2] = (u32)f2b(f0) | ((u32)f2b(f1) << 16);
        }
    }
}

// ---------------------------------------------------------------- emb pipeline
__global__ __launch_bounds__(256) void embsilu_kernel(const float* __restrict__ emb,
        float* __restrict__ se)
{
    const int i = blockIdx.x * 256 + threadIdx.x;
    if (i < CB * CTE) {
        const float e = emb[i];
        se[i] = e / (1.0f + __expf(-e));
    }
}
__global__ __launch_bounds__(256) void eoinit_kernel(const float* __restrict__ embB,
        float* __restrict__ eo)
{
    const int i = blockIdx.x * 256 + threadIdx.x;
    if (i < CB * CD2) eo[i] = embB[i & (CD2 - 1)];
}
__global__ __launch_bounds__(256) void embout2_kernel(const float* __restrict__ se,
        const float* __restrict__ embW, float* __restrict__ eo)
{
    const int jg = blockIdx.x & 15, kc = blockIdx.x >> 4;
    const int tid = threadIdx.x;
    const int jl = tid & 63, kgrp = tid >> 6;
    const int j = jg * 64 + jl;
    const int kbase = kc * 256 + kgrp * 64;
    const float* W = embW + (size_t)kbase * CD2 + j;
    const float* s0 = se + kbase;
    const float* s1 = s0 + CTE;
    const float* s2 = s1 + CTE;
    const float* s3 = s2 + CTE;
    float a0 = 0.0f, a1 = 0.0f, a2 = 0.0f, a3 = 0.0f;
#pragma unroll 8
    for (int kk = 0; kk < 64; kk++) {
        const float w = W[(size_t)kk * CD2];
        a0 = fmaf(s0[kk], w, a0);
        a1 = fmaf(s1[kk], w, a1);
        a2 = fmaf(s2[kk], w, a2);
        a3 = fmaf(s3[kk], w, a3);
    }
    __shared__ float red[4][4][64];   // [kgrp][b][j]
    red[kgrp][0][jl] = a0; red[kgrp][1][jl] = a1;
    red[kgrp][2][jl] = a2; red[kgrp][3][jl] = a3;
    __syncthreads();
    if (tid < 64) {
#pragma unroll
        for (int b = 0; b < 4; b++) {
            const float t = red[0][b][tid] + red[1][b][tid]
                          + red[2][b][tid] + red[3][b][tid];
            atomicAdd(&eo[(size_t)b * CD2 + jg * 64 + tid], t);
        }
    }
}

// ---------------------------------------------------------------- LN2 + stylization + silu: y bf16 -> s bf16
__global__ __launch_bounds__(256) void ln2_style_kernel(const u16* __restrict__ y,
        const float* __restrict__ g2, const float* __restrict__ bt2,
        const float* __restrict__ eo, u16* __restrict__ sout)
{
    const int row = blockIdx.x;
    const int tid = threadIdx.x;
    const int b = row >> 13;
    const u32 p = ((const u32*)(y + (size_t)row * CD))[tid];
    const float x0 = b2f((u16)(p & 0xffff));
    const float x1 = b2f((u16)(p >> 16));
    float s = x0 + x1;
    float sq = x0 * x0 + x1 * x1;
#pragma unroll
    for (int m = 1; m < 64; m <<= 1) { s += __shfl_xor(s, m); sq += __shfl_xor(sq, m); }
    __shared__ float red[8];
    const int wid = tid >> 6;
    if ((tid & 63) == 0) { red[wid] = s; red[wid + 4] = sq; }
    __syncthreads();
    s = red[0] + red[1] + red[2] + red[3];
    sq = red[4] + red[5] + red[6] + red[7];
    const float mu = s * (1.0f / CD);
    float var = sq * (1.0f / CD) - mu * mu;
    var = fmaxf(var, 0.0f);
    const float rs = rsqrtf(var + 1e-5f);
    const float2 gv = ((const float2*)g2)[tid];
    const float2 bv = ((const float2*)bt2)[tid];
    const float2 sc = ((const float2*)(eo + (size_t)b * CD2))[tid];
    const float2 sh = ((const float2*)(eo + (size_t)b * CD2 + CD))[tid];
    float h0 = (x0 - mu) * rs * gv.x + bv.x;
    float h1 = (x1 - mu) * rs * gv.y + bv.y;
    h0 = h0 * (1.0f + sc.x) + sh.x;
    h1 = h1 * (1.0f + sc.y) + sh.y;
    const float s0 = h0 / (1.0f + __expf(-h0));
    const float s1 = h1 / (1.0f + __expf(-h1));
    ((u32*)(sout + (size_t)row * CD))[tid] = (u32)f2b(s0) | ((u32)f2b(s1) << 16);
}

// ----------------------------------------------------------------
// Buffers:
//  d_out (64 MB fp32 out) as scratch until final GEMM:
//    R0 [0,32M):  k bf16 -> q bf16 (k dead after attn_mfma)
//    R1 [32M,64M): v bf16 -> y bf16
//  d_ws (~36.4 MB used):
//    ws+0        : xn bf16 (32 MB) -> s bf16
//    ws+33554432 : Wt bf16 x4 [n][k]: Wk,Wv,Wq,outW (2 MB)
//    ws+35651584 : pm/ps (512 KB, dead after ksm_norm) -> attn (512 KB fp32)
//    ws+36306944 : eo (16 KB fp32)
//    ws+36323328 : se (32 KB fp32, silu(emb))
extern "C" void kernel_launch(void* const* d_in, const int* in_sizes, int n_in,
                              void* d_out, int out_size, void* d_ws, size_t ws_size,
                              hipStream_t stream) {
    (void)in_sizes; (void)n_in; (void)out_size; (void)ws_size;
    const float* x    = (const float*)d_in[0];
    const float* emb  = (const float*)d_in[1];
    const float* mask = (const float*)d_in[2];
    const float* gamma= (const float*)d_in[3];
    const float* beta = (const float*)d_in[4];
    const float* Wq   = (const float*)d_in[5];
    const float* bq   = (const float*)d_in[6];
    const float* Wk   = (const float*)d_in[7];
    const float* bk   = (const float*)d_in[8];
    const float* Wv   = (const float*)d_in[9];
    const float* bv   = (const float*)d_in[10];
    const float* embW = (const float*)d_in[11];
    const float* embB = (const float*)d_in[12];
    const float* g2   = (const float*)d_in[13];
    const float* bt2  = (const float*)d_in[14];
    const float* outW = (const float*)d_in[15];
    const float* outb = (const float*)d_in[16];

    char* od = (char*)d_out;
    u16* kq  = (u16*)od;                        // R0: k then q
    u16* vy  = (u16*)(od + 33554432);           // R1: v then y
    float* outp = (float*)d_out;

    char* ws = (char*)d_ws;
    u16* xn   = (u16*)ws;                       // 32 MB, later s
    u16* WtK  = (u16*)(ws + 33554432);
    u16* WtV  = WtK + (size_t)CD * CD;
    u16* WtQ  = WtV + (size_t)CD * CD;
    u16* WtO  = WtQ + (size_t)CD * CD;
    float* pm   = (float*)(ws + 35651584);      // 256 KB
    float* ps   = (float*)(ws + 35651584 + 262144); // 256 KB
    float* attn = (float*)(ws + 35651584);      // reuses pm/ps region after ksm
    float* eo   = (float*)(ws + 36306944);
    float* se   = (float*)(ws + 36323328);

    wconv_kernel<<<dim3(64, 4), 256, 0, stream>>>(Wk, Wv, Wq, outW, WtK);
    ln1_kernel<<<CB * CT, 256, 0, stream>>>(x, gamma, beta, xn);
    embsilu_kernel<<<32, 256, 0, stream>>>(emb, se);
    eoinit_kernel<<<16, 256, 0, stream>>>(embB, eo);
    embout2_kernel<<<128, 256, 0, stream>>>(se, embW, eo);
    // fused k+v GEMM (mode 4): k -> kq, v -> vy
    gemm_mfma<<<512, 512, 0, stream>>>(xn, WtK, bk, bv, kq, vy, mask, nullptr, 4);
    ksm_partial<<<128, 256, 0, stream>>>(kq, pm, ps);
    ksm_norm<<<128, 256, 0, stream>>>(kq, pm, ps);
    zero_kernel<<<512, 256, 0, stream>>>(attn, CB * CH * CDH * CDH);
    attn_mfma<<<512, 256, 0, stream>>>(kq, vy, attn);
    // k, v dead -> q into R0, y into R1
    gemm_mfma<<<256, 512, 0, stream>>>(xn, WtQ, bq, nullptr, kq, nullptr, nullptr, nullptr, 0);
    y_mfma<<<1024, 256, 0, stream>>>(kq, attn, vy);
    ln2_style_kernel<<<CB * CT, 256, 0, stream>>>(vy, g2, bt2, eo, xn /* s */);
    gemm_mfma<<<256, 512, 0, stream>>>(xn /* s */, WtO, outb, nullptr, outp, nullptr, nullptr, x, 3);
}